// Round 3
// baseline (489.131 us; speedup 1.0000x reference)
//
#include <hip/hip_runtime.h>
#include <hip/hip_bf16.h>

typedef __hip_bfloat16 bf16;
typedef __attribute__((ext_vector_type(8))) short bf16x8;
typedef __attribute__((ext_vector_type(4))) float f32x4;

#define T_DIM 2048
#define B_DIM 8
#define E_DIM 512
#define N_DIM 1024
#define M_ROWS (T_DIM * B_DIM)   // 16384
#define NCHUNK 64
#define CLEN (T_DIM / NCHUNK)    // 32

__device__ __forceinline__ void gload16(const void* g, void* l) {
    __builtin_amdgcn_global_load_lds((const void __attribute__((address_space(1)))*)g,
                                     (void __attribute__((address_space(3)))*)l, 16, 0, 0);
}

// ---------- small prep: Lambda (complex), gamma ----------
__global__ void k_prep(const float* __restrict__ nu_log, const float* __restrict__ theta_log,
                       const float* __restrict__ gamma_log,
                       float* __restrict__ LamR, float* __restrict__ LamI, float* __restrict__ g) {
    int i = blockIdx.x * 256 + threadIdx.x;
    if (i < N_DIM) {
        float nu  = expf(nu_log[i]);
        float th  = expf(theta_log[i]);
        float mag = expf(-nu);
        LamR[i] = mag * cosf(th);
        LamI[i] = mag * sinf(th);
        g[i] = expf(gamma_log[i]);
    }
}

// ---------- elementwise fp32 -> bf16 convert (optional scalar multiply) ----------
struct __align__(8) bf4 { bf16 v[4]; };
__global__ void k_conv(const float* __restrict__ in, bf16* __restrict__ out, int n4, float mul) {
    int i = blockIdx.x * 256 + threadIdx.x;
    int stride = gridDim.x * 256;
    for (; i < n4; i += stride) {
        float4 v = ((const float4*)in)[i];
        bf4 o;
        o.v[0] = __float2bfloat16(v.x * mul);
        o.v[1] = __float2bfloat16(v.y * mul);
        o.v[2] = __float2bfloat16(v.z * mul);
        o.v[3] = __float2bfloat16(v.w * mul);
        ((bf4*)out)[i] = o;
    }
}

// ---------- transpose + convert: out[c,r] = in[r,c] * (scale ? scale[r] : 1) ----------
__global__ void k_transpose(const float* __restrict__ in, bf16* __restrict__ out,
                            const float* __restrict__ scale, int R, int C) {
    __shared__ float tile[32][33];
    int tx = threadIdx.x & 31, ty = threadIdx.x >> 5;
    int r0 = blockIdx.y * 32, c0 = blockIdx.x * 32;
#pragma unroll
    for (int i = 0; i < 32; i += 8) {
        int r = r0 + ty + i;
        float v = in[(size_t)r * C + c0 + tx];
        if (scale) v *= scale[r];
        tile[ty + i][tx] = v;
    }
    __syncthreads();
#pragma unroll
    for (int i = 0; i < 32; i += 8) {
        out[(size_t)(c0 + ty + i) * R + r0 + tx] = __float2bfloat16(tile[tx][ty + i]);
    }
}

// ---------- bias vectors ----------
__global__ void k_bias_bu(const float* __restrict__ b_in, const float* __restrict__ g,
                          const float* __restrict__ B_real, const float* __restrict__ B_imag,
                          float* __restrict__ c_bu) {
    int j = blockIdx.x * 256 + threadIdx.x;  // 0..2047
    if (j < 2048) {
        const float* B = (j < N_DIM) ? B_real : B_imag;
        int jj = j & (N_DIM - 1);
        float s = 0.f;
        for (int i = 0; i < N_DIM; ++i) s = fmaf(b_in[i] * g[i], B[(size_t)i * N_DIM + jj], s);
        c_bu[j] = s;
    }
}

__global__ void k_bias_out(const float* __restrict__ b_out, const float* __restrict__ b_in,
                           const float* __restrict__ D, const float* __restrict__ W_out,
                           float* __restrict__ bo) {
    int e = blockIdx.x * 256 + threadIdx.x;
    if (e < E_DIM) {
        float s = b_out[e];
        for (int j = 0; j < N_DIM; ++j) s = fmaf(b_in[j] * D[j], W_out[(size_t)j * E_DIM + e], s);
        bo[e] = s;
    }
}

// ---------- generic NT GEMM: out[M,N] = A[M,K] @ Bt[N,K]^T (+bias[n]) ----------
// 128x128 tile, 4 waves, mfma_f32_16x16x32_bf16, global_load_lds staging.
template <bool ASPLIT, bool OUTF32, bool BIAS>
__global__ __launch_bounds__(256)
void k_gemm(const bf16* __restrict__ A0, const bf16* __restrict__ A1, int ksplit,
            int lda0, int lda1, const bf16* __restrict__ Bt, int ldb,
            void* __restrict__ outp, int ldo, const float* __restrict__ bias, int K) {
    __shared__ __align__(16) bf16 lA[128 * 32];
    __shared__ __align__(16) bf16 lB[128 * 32];
    const int tid = threadIdx.x;
    const int bn = blockIdx.x, bm = blockIdx.y;
    const int lane = tid & 63, w = tid >> 6;
    const int wr = w >> 1, wc = w & 1;
    const int fr = lane & 15, fq = lane >> 4;
    f32x4 acc[4][4] = {};

    for (int k0 = 0; k0 < K; k0 += 32) {
        const bf16* Ap = A0;
        int lda = lda0, ac = k0;
        if (ASPLIT && k0 >= ksplit) { Ap = A1; lda = lda1; ac = k0 - ksplit; }
#pragma unroll
        for (int L = 0; L < 2; ++L) {
            int idx = L * 256 + tid;
            int rr = idx >> 2, kk = (idx & 3) * 8;
            gload16(Ap + (size_t)(bm * 128 + rr) * lda + ac + kk, lA + idx * 8);
            gload16(Bt + (size_t)(bn * 128 + rr) * ldb + k0 + kk, lB + idx * 8);
        }
        __syncthreads();
        bf16x8 af[4], bfr[4];
#pragma unroll
        for (int i = 0; i < 4; ++i)
            af[i] = *(const bf16x8*)(lA + (wr * 64 + i * 16 + fr) * 32 + fq * 8);
#pragma unroll
        for (int i = 0; i < 4; ++i)
            bfr[i] = *(const bf16x8*)(lB + (wc * 64 + i * 16 + fr) * 32 + fq * 8);
#pragma unroll
        for (int i = 0; i < 4; ++i)
#pragma unroll
            for (int j = 0; j < 4; ++j)
                acc[i][j] = __builtin_amdgcn_mfma_f32_16x16x32_bf16(af[i], bfr[j], acc[i][j], 0, 0, 0);
        __syncthreads();
    }
    const int orow = bm * 128 + wr * 64;
    const int ocol = bn * 128 + wc * 64;
#pragma unroll
    for (int i = 0; i < 4; ++i) {
#pragma unroll
        for (int j = 0; j < 4; ++j) {
            int col = ocol + j * 16 + fr;
            float bv = BIAS ? bias[col] : 0.0f;
#pragma unroll
            for (int r = 0; r < 4; ++r) {
                int row = orow + i * 16 + fq * 4 + r;
                float v = acc[i][j][r] + bv;
                if (OUTF32) ((float*)outp)[(size_t)row * ldo + col] = v;
                else        ((bf16*)outp)[(size_t)row * ldo + col] = __float2bfloat16(v);
            }
        }
    }
}

// ---------- chunked linear scan over time ----------
// BuH layout: row (t*8+b), cols [0,1024)=real, [1024,2048)=imag, bf16.
__global__ void k_scan_carry(const bf16* __restrict__ BuH, const float* __restrict__ LamR,
                             const float* __restrict__ LamI, float2* __restrict__ carry) {
    int tid = blockIdx.x * 256 + threadIdx.x;  // [0, NCHUNK*8192)
    int n = tid & (N_DIM - 1);
    int bb = (tid >> 10) & 7;
    int c = tid >> 13;
    float lr = LamR[n], li = LamI[n];
    float hr = 0.f, hi = 0.f;
    const bf16* p = BuH + ((size_t)(c * CLEN) * B_DIM + bb) * 2048 + n;
#pragma unroll 8
    for (int t = 0; t < CLEN; ++t) {
        float br = __bfloat162float(p[0]);
        float bi = __bfloat162float(p[N_DIM]);
        float nr = fmaf(lr, hr, fmaf(-li, hi, br));
        float ni = fmaf(lr, hi, fmaf(li, hr, bi));
        hr = nr; hi = ni;
        p += B_DIM * 2048;
    }
    carry[tid] = make_float2(hr, hi);
}

__global__ void k_scan_combine(const float2* __restrict__ carry, float2* __restrict__ S,
                               const float* __restrict__ LamR, const float* __restrict__ LamI) {
    int tid = blockIdx.x * 256 + threadIdx.x;  // [0, 8192)
    int n = tid & (N_DIM - 1);
    float ar = LamR[n], ai = LamI[n];
#pragma unroll
    for (int s = 0; s < 5; ++s) { float nr = ar * ar - ai * ai, ni = 2.f * ar * ai; ar = nr; ai = ni; }  // Lam^32
    float sr = 0.f, si = 0.f;
    for (int c = 0; c < NCHUNK; ++c) {
        S[(size_t)c * 8192 + tid] = make_float2(sr, si);
        float2 ca = carry[(size_t)c * 8192 + tid];
        float nr = fmaf(ar, sr, fmaf(-ai, si, ca.x));
        float ni = fmaf(ar, si, fmaf(ai, sr, ca.y));
        sr = nr; si = ni;
    }
}

__global__ void k_scan_apply(bf16* __restrict__ BuH, const float* __restrict__ LamR,
                             const float* __restrict__ LamI, const float2* __restrict__ S) {
    int tid = blockIdx.x * 256 + threadIdx.x;
    int n = tid & (N_DIM - 1);
    int bb = (tid >> 10) & 7;
    int c = tid >> 13;
    float lr = LamR[n], li = LamI[n];
    float2 s0 = S[tid];
    float hr = s0.x, hi = s0.y;
    bf16* p = BuH + ((size_t)(c * CLEN) * B_DIM + bb) * 2048 + n;
#pragma unroll 8
    for (int t = 0; t < CLEN; ++t) {
        float br = __bfloat162float(p[0]);
        float bi = __bfloat162float(p[N_DIM]);
        float nr = fmaf(lr, hr, fmaf(-li, hi, br));
        float ni = fmaf(lr, hi, fmaf(li, hr, bi));
        hr = nr; hi = ni;
        p[0] = __float2bfloat16(hr);
        p[N_DIM] = __float2bfloat16(hi);
        p += B_DIM * 2048;
    }
}

extern "C" void kernel_launch(void* const* d_in, const int* in_sizes, int n_in,
                              void* d_out, int out_size, void* d_ws, size_t ws_size,
                              hipStream_t stream) {
    const float* x         = (const float*)d_in[0];
    const float* W_in      = (const float*)d_in[1];
    const float* b_in      = (const float*)d_in[2];
    const float* W_out     = (const float*)d_in[3];
    const float* b_out     = (const float*)d_in[4];
    const float* nu_log    = (const float*)d_in[5];
    const float* theta_log = (const float*)d_in[6];
    const float* gamma_log = (const float*)d_in[7];
    const float* B_real    = (const float*)d_in[8];
    const float* B_imag    = (const float*)d_in[9];
    const float* C_real    = (const float*)d_in[10];
    const float* C_imag    = (const float*)d_in[11];
    const float* Dvec      = (const float*)d_in[12];
    float* out = (float*)d_out;

    char* ws = (char*)d_ws;
    size_t off = 0;
    auto alloc = [&](size_t bytes) { void* p = ws + off; off = (off + bytes + 255) & ~(size_t)255; return p; };
    bf16*  xb    = (bf16*)alloc((size_t)M_ROWS * E_DIM * 2);
    bf16*  BuH   = (bf16*)alloc((size_t)M_ROWS * 2048 * 2);
    bf16*  BscT  = (bf16*)alloc((size_t)2048 * 1024 * 2);
    bf16*  Win_b = (bf16*)alloc((size_t)512 * 1024 * 2);
    bf16*  Cr_b  = (bf16*)alloc((size_t)1024 * 1024 * 2);
    bf16*  Ci_b  = (bf16*)alloc((size_t)1024 * 1024 * 2);
    bf16*  WoT   = (bf16*)alloc((size_t)512 * 1024 * 2);
    bf16*  WoTD  = (bf16*)alloc((size_t)512 * 1024 * 2);
    bf16*  WBcat = (bf16*)alloc((size_t)2048 * 512 * 2);
    bf16*  Bfin  = (bf16*)alloc((size_t)512 * 2560 * 2);
    float* LamR  = (float*)alloc(1024 * 4);
    float* LamI  = (float*)alloc(1024 * 4);
    float* gvec  = (float*)alloc(1024 * 4);
    float* c_bu  = (float*)alloc(2048 * 4);
    float* biasO = (float*)alloc(512 * 4);
    float2* carry = (float2*)alloc((size_t)NCHUNK * 8192 * 8);
    float2* Sbuf  = (float2*)alloc((size_t)NCHUNK * 8192 * 8);

    // prep + converts
    k_prep<<<4, 256, 0, stream>>>(nu_log, theta_log, gamma_log, LamR, LamI, gvec);
    k_conv<<<2048, 256, 0, stream>>>(x, xb, M_ROWS * E_DIM / 4, 1.f);
    k_conv<<<512, 256, 0, stream>>>(W_in, Win_b, 512 * 1024 / 4, 1.f);
    k_conv<<<1024, 256, 0, stream>>>(C_real, Cr_b, 1024 * 1024 / 4, 1.f);
    k_conv<<<1024, 256, 0, stream>>>(C_imag, Ci_b, 1024 * 1024 / 4, -1.f);  // negated: -C_i
    k_transpose<<<dim3(32, 32), 256, 0, stream>>>(B_real, BscT, gvec, 1024, 1024);
    k_transpose<<<dim3(32, 32), 256, 0, stream>>>(B_imag, BscT + (size_t)1024 * 1024, gvec, 1024, 1024);
    k_transpose<<<dim3(16, 32), 256, 0, stream>>>(W_out, WoT, nullptr, 1024, 512);
    k_transpose<<<dim3(16, 32), 256, 0, stream>>>(W_out, WoTD, Dvec, 1024, 512);
    k_bias_bu<<<8, 256, 0, stream>>>(b_in, gvec, B_real, B_imag, c_bu);
    k_bias_out<<<2, 256, 0, stream>>>(b_out, b_in, Dvec, W_out, biasO);

    // precompute folds (bf16 MFMA)
    // WBcat[2048,512]: WBcat[j,e] = sum_i BscT[j,i]*W_in[e,i]
    k_gemm<false, false, false><<<dim3(4, 16), 256, 0, stream>>>(BscT, nullptr, 0, 1024, 0, Win_b, 1024, WBcat, 512, nullptr, 1024);
    // Bfin[512,2560]: cols [0,1024)=C_r@W_out ^T, [1024,2048)=-(C_i@W_out)^T, [2048,2560)=W_xout^T
    k_gemm<false, false, false><<<dim3(8, 4), 256, 0, stream>>>(WoT, nullptr, 0, 1024, 0, Cr_b, 1024, Bfin, 2560, nullptr, 1024);
    k_gemm<false, false, false><<<dim3(8, 4), 256, 0, stream>>>(WoT, nullptr, 0, 1024, 0, Ci_b, 1024, Bfin + 1024, 2560, nullptr, 1024);
    k_gemm<false, false, false><<<dim3(4, 4), 256, 0, stream>>>(WoTD, nullptr, 0, 1024, 0, Win_b, 1024, Bfin + 2048, 2560, nullptr, 1024);

    // G1: BuH[16384,2048] = xb @ WBcat^T + c_bu   (Bu real|imag)
    k_gemm<false, false, true><<<dim3(16, 128), 256, 0, stream>>>(xb, nullptr, 0, 512, 0, WBcat, 512, BuH, 2048, c_bu, 512);

    // scan: h_t = Lam*h_{t-1} + Bu_t  (in place, bf16 out)
    k_scan_carry<<<NCHUNK * 8192 / 256, 256, 0, stream>>>(BuH, LamR, LamI, carry);
    k_scan_combine<<<32, 256, 0, stream>>>(carry, Sbuf, LamR, LamI);
    k_scan_apply<<<NCHUNK * 8192 / 256, 256, 0, stream>>>(BuH, LamR, LamI, Sbuf);

    // G2: out[16384,512] = [h_r|h_i|xb] @ Bfin^T + biasO
    k_gemm<true, true, true><<<dim3(4, 128), 256, 0, stream>>>(BuH, xb, 2048, 2048, 512, Bfin, 2560, out, 512, biasO, 2560);
}

// Round 4
// 412.414 us; speedup vs baseline: 1.1860x; 1.1860x over previous
//
#include <hip/hip_runtime.h>
#include <hip/hip_bf16.h>

typedef __hip_bfloat16 bf16;
typedef __attribute__((ext_vector_type(8))) short bf16x8;
typedef __attribute__((ext_vector_type(4))) float f32x4;

#define T_DIM 2048
#define B_DIM 8
#define E_DIM 512
#define N_DIM 1024
#define M_ROWS (T_DIM * B_DIM)   // 16384
#define NCHUNK 64
#define CLEN (T_DIM / NCHUNK)    // 32

__device__ __forceinline__ void gload16(const void* g, void* l) {
    __builtin_amdgcn_global_load_lds((const void __attribute__((address_space(1)))*)g,
                                     (void __attribute__((address_space(3)))*)l, 16, 0, 0);
}

// ---------- small prep: Lambda (complex), gamma ----------
__global__ void k_prep(const float* __restrict__ nu_log, const float* __restrict__ theta_log,
                       const float* __restrict__ gamma_log,
                       float* __restrict__ LamR, float* __restrict__ LamI, float* __restrict__ g) {
    int i = blockIdx.x * 256 + threadIdx.x;
    if (i < N_DIM) {
        float nu  = expf(nu_log[i]);
        float th  = expf(theta_log[i]);
        float mag = expf(-nu);
        LamR[i] = mag * cosf(th);
        LamI[i] = mag * sinf(th);
        g[i] = expf(gamma_log[i]);
    }
}

// ---------- elementwise fp32 -> bf16 convert (optional scalar multiply) ----------
struct __align__(8) bf4 { bf16 v[4]; };
__global__ void k_conv(const float* __restrict__ in, bf16* __restrict__ out, int n4, float mul) {
    int i = blockIdx.x * 256 + threadIdx.x;
    int stride = gridDim.x * 256;
    for (; i < n4; i += stride) {
        float4 v = ((const float4*)in)[i];
        bf4 o;
        o.v[0] = __float2bfloat16(v.x * mul);
        o.v[1] = __float2bfloat16(v.y * mul);
        o.v[2] = __float2bfloat16(v.z * mul);
        o.v[3] = __float2bfloat16(v.w * mul);
        ((bf4*)out)[i] = o;
    }
}

// ---------- transpose + convert: out[c,r] = in[r,c] * (scale ? scale[r] : 1) ----------
__global__ void k_transpose(const float* __restrict__ in, bf16* __restrict__ out,
                            const float* __restrict__ scale, int R, int C) {
    __shared__ float tile[32][33];
    int tx = threadIdx.x & 31, ty = threadIdx.x >> 5;
    int r0 = blockIdx.y * 32, c0 = blockIdx.x * 32;
#pragma unroll
    for (int i = 0; i < 32; i += 8) {
        int r = r0 + ty + i;
        float v = in[(size_t)r * C + c0 + tx];
        if (scale) v *= scale[r];
        tile[ty + i][tx] = v;
    }
    __syncthreads();
#pragma unroll
    for (int i = 0; i < 32; i += 8) {
        out[(size_t)(c0 + ty + i) * R + r0 + tx] = __float2bfloat16(tile[tx][ty + i]);
    }
}

// ---------- bias vectors (K-chunk parallel + atomic reduce; buffers pre-zeroed) ----------
__global__ void k_bias_bu(const float* __restrict__ b_in, const float* __restrict__ g,
                          const float* __restrict__ B_real, const float* __restrict__ B_imag,
                          float* __restrict__ c_bu) {
    int id = blockIdx.x;              // 64 = 8 j-blocks x 8 i-chunks
    int jblk = id & 7, ic = id >> 3;
    int j = jblk * 256 + threadIdx.x; // 0..2047
    const float* B = (j < N_DIM) ? B_real : B_imag;
    int jj = j & (N_DIM - 1);
    float s = 0.f;
    for (int i = ic * 128; i < ic * 128 + 128; ++i)
        s = fmaf(b_in[i] * g[i], B[(size_t)i * N_DIM + jj], s);
    atomicAdd(&c_bu[j], s);
}

__global__ void k_bias_out(const float* __restrict__ b_out, const float* __restrict__ b_in,
                           const float* __restrict__ D, const float* __restrict__ W_out,
                           float* __restrict__ bo) {
    int id = blockIdx.x;              // 16 = 2 e-blocks x 8 j-chunks
    int eblk = id & 1, ic = id >> 1;
    int e = eblk * 256 + threadIdx.x;
    float s = (ic == 0) ? b_out[e] : 0.f;
    for (int j = ic * 128; j < ic * 128 + 128; ++j)
        s = fmaf(b_in[j] * D[j], W_out[(size_t)j * E_DIM + e], s);
    atomicAdd(&bo[e], s);
}

// ---------- shared 128x128 GEMM core: out[M,N] = A[M,K] @ Bt[N,K]^T (+bias) ----------
template <bool BIAS>
__device__ __forceinline__ void gemm128_core(bf16* lA, bf16* lB,
        const bf16* __restrict__ A, int lda, const bf16* __restrict__ Bt, int ldb,
        bf16* __restrict__ outp, int ldo, const float* __restrict__ bias, int K,
        int bn, int bm) {
    const int tid = threadIdx.x;
    const int lane = tid & 63, w = tid >> 6;
    const int wr = w >> 1, wc = w & 1;
    const int fr = lane & 15, fq = lane >> 4;
    f32x4 acc[4][4] = {};
    for (int k0 = 0; k0 < K; k0 += 32) {
#pragma unroll
        for (int L = 0; L < 2; ++L) {
            int idx = L * 256 + tid;
            int rr = idx >> 2, kk = (idx & 3) * 8;
            gload16(A + (size_t)(bm * 128 + rr) * lda + k0 + kk, lA + idx * 8);
            gload16(Bt + (size_t)(bn * 128 + rr) * ldb + k0 + kk, lB + idx * 8);
        }
        __syncthreads();
        bf16x8 af[4], bfr[4];
#pragma unroll
        for (int i = 0; i < 4; ++i)
            af[i] = *(const bf16x8*)(lA + (wr * 64 + i * 16 + fr) * 32 + fq * 8);
#pragma unroll
        for (int i = 0; i < 4; ++i)
            bfr[i] = *(const bf16x8*)(lB + (wc * 64 + i * 16 + fr) * 32 + fq * 8);
#pragma unroll
        for (int i = 0; i < 4; ++i)
#pragma unroll
            for (int j = 0; j < 4; ++j)
                acc[i][j] = __builtin_amdgcn_mfma_f32_16x16x32_bf16(af[i], bfr[j], acc[i][j], 0, 0, 0);
        __syncthreads();
    }
    const int orow = bm * 128 + wr * 64;
    const int ocol = bn * 128 + wc * 64;
#pragma unroll
    for (int i = 0; i < 4; ++i)
#pragma unroll
        for (int j = 0; j < 4; ++j) {
            int col = ocol + j * 16 + fr;
            float bv = BIAS ? bias[col] : 0.0f;
#pragma unroll
            for (int r = 0; r < 4; ++r) {
                int row = orow + i * 16 + fq * 4 + r;
                outp[(size_t)row * ldo + col] = __float2bfloat16(acc[i][j][r] + bv);
            }
        }
}

// ---------- G1: BuH[16384,2048] = xb @ WBcat^T + c_bu, XCD-swizzled ----------
__global__ __launch_bounds__(256)
void k_g1(const bf16* __restrict__ xb, const bf16* __restrict__ WBcat,
          bf16* __restrict__ BuH, const float* __restrict__ c_bu) {
    __shared__ __align__(16) bf16 lA[128 * 32];
    __shared__ __align__(16) bf16 lB[128 * 32];
    int id = blockIdx.x;                       // 2048, %8==0 -> bijective chunk swizzle
    int swz = (id & 7) * 256 + (id >> 3);
    int bn = swz & 15, bm = swz >> 4;          // per XCD: 16 bm-panels x all 16 bn
    gemm128_core<true>(lA, lB, xb, 512, WBcat, 512, BuH, 2048, c_bu, 512, bn, bm);
}

// ---------- batched small precompute GEMMs (one launch, 144 blocks) ----------
__global__ __launch_bounds__(256)
void k_gemm4(const bf16* __restrict__ BscT, const bf16* __restrict__ Win_b,
             const bf16* __restrict__ WoT, const bf16* __restrict__ WoTD,
             const bf16* __restrict__ Cr_b, const bf16* __restrict__ Ci_b,
             bf16* __restrict__ WBcat, bf16* __restrict__ Bfin) {
    __shared__ __align__(16) bf16 lA[128 * 32];
    __shared__ __align__(16) bf16 lB[128 * 32];
    int id = blockIdx.x;
    if (id < 64) {        // WBcat[2048,512] = BscT @ Win_b^T
        gemm128_core<false>(lA, lB, BscT, 1024, Win_b, 1024, WBcat, 512, nullptr, 1024, id & 3, id >> 2);
    } else if (id < 96) { // Bfin[:, 0:1024) = WoT @ Cr_b^T
        int l = id - 64;
        gemm128_core<false>(lA, lB, WoT, 1024, Cr_b, 1024, Bfin, 2560, nullptr, 1024, l & 7, l >> 3);
    } else if (id < 128) {// Bfin[:, 1024:2048) = WoT @ (-Ci)^T
        int l = id - 96;
        gemm128_core<false>(lA, lB, WoT, 1024, Ci_b, 1024, Bfin + 1024, 2560, nullptr, 1024, l & 7, l >> 3);
    } else {              // Bfin[:, 2048:2560) = WoTD @ Win_b^T
        int l = id - 128;
        gemm128_core<false>(lA, lB, WoTD, 1024, Win_b, 1024, Bfin + 2048, 2560, nullptr, 1024, l & 3, l >> 2);
    }
}

// ---------- G2 wide-N: out[16384,512] = [h_r|h_i|xb] @ Bfin^T + biasO ----------
// BM=64, BN=512 (full N): A fetched once from HBM; Bfin L2-resident per XCD.
// Double-buffered LDS, stage-next-before-compute, one barrier per K-step.
// 4-slot XOR swizzle: linear LDS dest + inverse-swizzled global src + swizzled read.
template <bool ASPLIT>
__global__ __launch_bounds__(256, 1)
void k_gemm_wn(const bf16* __restrict__ A0, const bf16* __restrict__ A1, int ksplit,
               int lda0, int lda1, const bf16* __restrict__ Bt, int ldb,
               float* __restrict__ outp, int ldo, const float* __restrict__ bias, int K) {
    __shared__ __align__(16) bf16 lA[2][64 * 32];
    __shared__ __align__(16) bf16 lB[2][512 * 32];
    const int tid = threadIdx.x;
    const int bm = blockIdx.x;
    const int lane = tid & 63, w = tid >> 6;
    const int fr = lane & 15, fq = lane >> 4;
    f32x4 acc[4][8] = {};
    const int nt = K / 32;

    auto stage = [&](int buf, int t) {
        int k0 = t * 32;
        const bf16* Ap = A0; int lda = lda0, ac = k0;
        if (ASPLIT && k0 >= ksplit) { Ap = A1; lda = lda1; ac = k0 - ksplit; }
        {
            int rr = tid >> 2, s = tid & 3;
            int kk = (s ^ (rr & 3)) * 8;   // inverse (==forward, involution) swizzle on src
            gload16(Ap + (size_t)(bm * 64 + rr) * lda + ac + kk, &lA[buf][tid * 8]);
        }
#pragma unroll
        for (int L = 0; L < 8; ++L) {
            int idx = L * 256 + tid;
            int rr = idx >> 2, s = idx & 3;
            int kk = (s ^ (rr & 3)) * 8;
            gload16(Bt + (size_t)rr * ldb + k0 + kk, &lB[buf][idx * 8]);
        }
    };

    stage(0, 0);
    __syncthreads();
    int cur = 0;
    for (int t = 0; t < nt; ++t) {
        if (t + 1 < nt) stage(cur ^ 1, t + 1);   // overlap next-tile HBM under compute
        bf16x8 af[4], bfr[8];
#pragma unroll
        for (int i = 0; i < 4; ++i) {
            int rr = i * 16 + fr;
            af[i] = *(const bf16x8*)(&lA[cur][(rr * 4 + (fq ^ (rr & 3))) * 8]);
        }
#pragma unroll
        for (int j = 0; j < 8; ++j) {
            int rr = w * 128 + j * 16 + fr;
            bfr[j] = *(const bf16x8*)(&lB[cur][(rr * 4 + (fq ^ (rr & 3))) * 8]);
        }
#pragma unroll
        for (int i = 0; i < 4; ++i)
#pragma unroll
            for (int j = 0; j < 8; ++j)
                acc[i][j] = __builtin_amdgcn_mfma_f32_16x16x32_bf16(af[i], bfr[j], acc[i][j], 0, 0, 0);
        __syncthreads();                         // drains vmcnt (stage done) + lgkm
        cur ^= 1;
    }
    const int orow = bm * 64;
#pragma unroll
    for (int i = 0; i < 4; ++i)
#pragma unroll
        for (int j = 0; j < 8; ++j) {
            int col = w * 128 + j * 16 + fr;
            float bv = bias[col];
#pragma unroll
            for (int r = 0; r < 4; ++r)
                outp[(size_t)(orow + i * 16 + fq * 4 + r) * ldo + col] = acc[i][j][r] + bv;
        }
}

// ---------- chunked linear scan over time ----------
__global__ void k_scan_carry(const bf16* __restrict__ BuH, const float* __restrict__ LamR,
                             const float* __restrict__ LamI, float2* __restrict__ carry) {
    int tid = blockIdx.x * 256 + threadIdx.x;  // [0, NCHUNK*8192)
    int n = tid & (N_DIM - 1);
    int bb = (tid >> 10) & 7;
    int c = tid >> 13;
    float lr = LamR[n], li = LamI[n];
    float hr = 0.f, hi = 0.f;
    const bf16* p = BuH + ((size_t)(c * CLEN) * B_DIM + bb) * 2048 + n;
#pragma unroll 8
    for (int t = 0; t < CLEN; ++t) {
        float br = __bfloat162float(p[0]);
        float bi = __bfloat162float(p[N_DIM]);
        float nr = fmaf(lr, hr, fmaf(-li, hi, br));
        float ni = fmaf(lr, hi, fmaf(li, hr, bi));
        hr = nr; hi = ni;
        p += B_DIM * 2048;
    }
    carry[tid] = make_float2(hr, hi);
}

__global__ void k_scan_combine(const float2* __restrict__ carry, float2* __restrict__ S,
                               const float* __restrict__ LamR, const float* __restrict__ LamI) {
    int tid = blockIdx.x * 256 + threadIdx.x;  // [0, 8192)
    int n = tid & (N_DIM - 1);
    float ar = LamR[n], ai = LamI[n];
#pragma unroll
    for (int s = 0; s < 5; ++s) { float nr = ar * ar - ai * ai, ni = 2.f * ar * ai; ar = nr; ai = ni; }  // Lam^32
    float sr = 0.f, si = 0.f;
    for (int c = 0; c < NCHUNK; ++c) {
        S[(size_t)c * 8192 + tid] = make_float2(sr, si);
        float2 ca = carry[(size_t)c * 8192 + tid];
        float nr = fmaf(ar, sr, fmaf(-ai, si, ca.x));
        float ni = fmaf(ar, si, fmaf(ai, sr, ca.y));
        sr = nr; si = ni;
    }
}

__global__ void k_scan_apply(bf16* __restrict__ BuH, const float* __restrict__ LamR,
                             const float* __restrict__ LamI, const float2* __restrict__ S) {
    int tid = blockIdx.x * 256 + threadIdx.x;
    int n = tid & (N_DIM - 1);
    int bb = (tid >> 10) & 7;
    int c = tid >> 13;
    float lr = LamR[n], li = LamI[n];
    float2 s0 = S[tid];
    float hr = s0.x, hi = s0.y;
    bf16* p = BuH + ((size_t)(c * CLEN) * B_DIM + bb) * 2048 + n;
#pragma unroll 8
    for (int t = 0; t < CLEN; ++t) {
        float br = __bfloat162float(p[0]);
        float bi = __bfloat162float(p[N_DIM]);
        float nr = fmaf(lr, hr, fmaf(-li, hi, br));
        float ni = fmaf(lr, hi, fmaf(li, hr, bi));
        hr = nr; hi = ni;
        p[0] = __float2bfloat16(hr);
        p[N_DIM] = __float2bfloat16(hi);
        p += B_DIM * 2048;
    }
}

extern "C" void kernel_launch(void* const* d_in, const int* in_sizes, int n_in,
                              void* d_out, int out_size, void* d_ws, size_t ws_size,
                              hipStream_t stream) {
    const float* x         = (const float*)d_in[0];
    const float* W_in      = (const float*)d_in[1];
    const float* b_in      = (const float*)d_in[2];
    const float* W_out     = (const float*)d_in[3];
    const float* b_out     = (const float*)d_in[4];
    const float* nu_log    = (const float*)d_in[5];
    const float* theta_log = (const float*)d_in[6];
    const float* gamma_log = (const float*)d_in[7];
    const float* B_real    = (const float*)d_in[8];
    const float* B_imag    = (const float*)d_in[9];
    const float* C_real    = (const float*)d_in[10];
    const float* C_imag    = (const float*)d_in[11];
    const float* Dvec      = (const float*)d_in[12];
    float* out = (float*)d_out;

    char* ws = (char*)d_ws;
    size_t off = 0;
    auto alloc = [&](size_t bytes) { void* p = ws + off; off = (off + bytes + 255) & ~(size_t)255; return p; };
    bf16*  xb    = (bf16*)alloc((size_t)M_ROWS * E_DIM * 2);
    bf16*  BuH   = (bf16*)alloc((size_t)M_ROWS * 2048 * 2);
    bf16*  BscT  = (bf16*)alloc((size_t)2048 * 1024 * 2);
    bf16*  Win_b = (bf16*)alloc((size_t)512 * 1024 * 2);
    bf16*  Cr_b  = (bf16*)alloc((size_t)1024 * 1024 * 2);
    bf16*  Ci_b  = (bf16*)alloc((size_t)1024 * 1024 * 2);
    bf16*  WoT   = (bf16*)alloc((size_t)512 * 1024 * 2);
    bf16*  WoTD  = (bf16*)alloc((size_t)512 * 1024 * 2);
    bf16*  WBcat = (bf16*)alloc((size_t)2048 * 512 * 2);
    bf16*  Bfin  = (bf16*)alloc((size_t)512 * 2560 * 2);
    float* LamR  = (float*)alloc(1024 * 4);
    float* LamI  = (float*)alloc(1024 * 4);
    float* gvec  = (float*)alloc(1024 * 4);
    float* c_bu  = (float*)alloc(2048 * 4);
    float* biasO = (float*)alloc(512 * 4);
    float2* carry = (float2*)alloc((size_t)NCHUNK * 8192 * 8);
    float2* Sbuf  = (float2*)alloc((size_t)NCHUNK * 8192 * 8);

    // prep + converts
    k_prep<<<4, 256, 0, stream>>>(nu_log, theta_log, gamma_log, LamR, LamI, gvec);
    k_conv<<<2048, 256, 0, stream>>>(x, xb, M_ROWS * E_DIM / 4, 1.f);
    k_conv<<<512, 256, 0, stream>>>(W_in, Win_b, 512 * 1024 / 4, 1.f);
    k_conv<<<1024, 256, 0, stream>>>(C_real, Cr_b, 1024 * 1024 / 4, 1.f);
    k_conv<<<1024, 256, 0, stream>>>(C_imag, Ci_b, 1024 * 1024 / 4, -1.f);  // negated: -C_i
    k_transpose<<<dim3(32, 32), 256, 0, stream>>>(B_real, BscT, gvec, 1024, 1024);
    k_transpose<<<dim3(32, 32), 256, 0, stream>>>(B_imag, BscT + (size_t)1024 * 1024, gvec, 1024, 1024);
    k_transpose<<<dim3(16, 32), 256, 0, stream>>>(W_out, WoT, nullptr, 1024, 512);
    k_transpose<<<dim3(16, 32), 256, 0, stream>>>(W_out, WoTD, Dvec, 1024, 512);

    // bias vectors (zero first; ws is re-poisoned 0xAA before every call)
    hipMemsetAsync(c_bu, 0, 2048 * 4, stream);
    hipMemsetAsync(biasO, 0, 512 * 4, stream);
    k_bias_bu<<<64, 256, 0, stream>>>(b_in, gvec, B_real, B_imag, c_bu);
    k_bias_out<<<16, 256, 0, stream>>>(b_out, b_in, Dvec, W_out, biasO);

    // precompute folds: one batched launch (144 blocks)
    k_gemm4<<<144, 256, 0, stream>>>(BscT, Win_b, WoT, WoTD, Cr_b, Ci_b, WBcat, Bfin);

    // G1: BuH[16384,2048] = xb @ WBcat^T + c_bu   (Bu real|imag)
    k_g1<<<2048, 256, 0, stream>>>(xb, WBcat, BuH, c_bu);

    // scan: h_t = Lam*h_{t-1} + Bu_t  (in place, bf16 out)
    k_scan_carry<<<NCHUNK * 8192 / 256, 256, 0, stream>>>(BuH, LamR, LamI, carry);
    k_scan_combine<<<32, 256, 0, stream>>>(carry, Sbuf, LamR, LamI);
    k_scan_apply<<<NCHUNK * 8192 / 256, 256, 0, stream>>>(BuH, LamR, LamI, Sbuf);

    // G2 wide-N: out[16384,512] = [h_r|h_i|xb] @ Bfin^T + biasO
    k_gemm_wn<true><<<256, 256, 0, stream>>>(BuH, xb, 2048, 2048, 512, Bfin, 2560, out, 512, biasO, 2560);
}

// Round 6
// 378.434 us; speedup vs baseline: 1.2925x; 1.0898x over previous
//
#include <hip/hip_runtime.h>
#include <hip/hip_bf16.h>

typedef __hip_bfloat16 bf16;
typedef __attribute__((ext_vector_type(8))) short bf16x8;
typedef __attribute__((ext_vector_type(4))) float f32x4;

#define T_DIM 2048
#define B_DIM 8
#define E_DIM 512
#define N_DIM 1024
#define M_ROWS (T_DIM * B_DIM)   // 16384
#define NCHUNK 64
#define CLEN (T_DIM / NCHUNK)    // 32

__device__ __forceinline__ void gload16(const void* g, void* l) {
    __builtin_amdgcn_global_load_lds((const void __attribute__((address_space(1)))*)g,
                                     (void __attribute__((address_space(3)))*)l, 16, 0, 0);
}

// ---------- small prep: Lambda (complex), gamma ----------
__global__ void k_prep(const float* __restrict__ nu_log, const float* __restrict__ theta_log,
                       const float* __restrict__ gamma_log,
                       float* __restrict__ LamR, float* __restrict__ LamI, float* __restrict__ g) {
    int i = blockIdx.x * 256 + threadIdx.x;
    if (i < N_DIM) {
        float nu  = expf(nu_log[i]);
        float th  = expf(theta_log[i]);
        float mag = expf(-nu);
        LamR[i] = mag * cosf(th);
        LamI[i] = mag * sinf(th);
        g[i] = expf(gamma_log[i]);
    }
}

// ---------- elementwise fp32 -> bf16 convert (optional scalar multiply) ----------
struct __align__(8) bf4 { bf16 v[4]; };
__global__ void k_conv(const float* __restrict__ in, bf16* __restrict__ out, int n4, float mul) {
    int i = blockIdx.x * 256 + threadIdx.x;
    int stride = gridDim.x * 256;
    for (; i < n4; i += stride) {
        float4 v = ((const float4*)in)[i];
        bf4 o;
        o.v[0] = __float2bfloat16(v.x * mul);
        o.v[1] = __float2bfloat16(v.y * mul);
        o.v[2] = __float2bfloat16(v.z * mul);
        o.v[3] = __float2bfloat16(v.w * mul);
        ((bf4*)out)[i] = o;
    }
}

// ---------- transpose + convert: out[c,r] = in[r,c] * (scale ? scale[r] : 1) ----------
__global__ void k_transpose(const float* __restrict__ in, bf16* __restrict__ out,
                            const float* __restrict__ scale, int R, int C) {
    __shared__ float tile[32][33];
    int tx = threadIdx.x & 31, ty = threadIdx.x >> 5;
    int r0 = blockIdx.y * 32, c0 = blockIdx.x * 32;
#pragma unroll
    for (int i = 0; i < 32; i += 8) {
        int r = r0 + ty + i;
        float v = in[(size_t)r * C + c0 + tx];
        if (scale) v *= scale[r];
        tile[ty + i][tx] = v;
    }
    __syncthreads();
#pragma unroll
    for (int i = 0; i < 32; i += 8) {
        out[(size_t)(c0 + ty + i) * R + r0 + tx] = __float2bfloat16(tile[tx][ty + i]);
    }
}

// ---------- bias vectors (K-chunk parallel + atomic reduce; buffers pre-zeroed) ----------
__global__ void k_bias_bu(const float* __restrict__ b_in, const float* __restrict__ g,
                          const float* __restrict__ B_real, const float* __restrict__ B_imag,
                          float* __restrict__ c_bu) {
    int id = blockIdx.x;              // 64 = 8 j-blocks x 8 i-chunks
    int jblk = id & 7, ic = id >> 3;
    int j = jblk * 256 + threadIdx.x; // 0..2047
    const float* B = (j < N_DIM) ? B_real : B_imag;
    int jj = j & (N_DIM - 1);
    float s = 0.f;
    for (int i = ic * 128; i < ic * 128 + 128; ++i)
        s = fmaf(b_in[i] * g[i], B[(size_t)i * N_DIM + jj], s);
    atomicAdd(&c_bu[j], s);
}

__global__ void k_bias_out(const float* __restrict__ b_out, const float* __restrict__ b_in,
                           const float* __restrict__ D, const float* __restrict__ W_out,
                           float* __restrict__ bo) {
    int id = blockIdx.x;              // 16 = 2 e-blocks x 8 j-chunks
    int eblk = id & 1, ic = id >> 1;
    int e = eblk * 256 + threadIdx.x;
    float s = (ic == 0) ? b_out[e] : 0.f;
    for (int j = ic * 128; j < ic * 128 + 128; ++j)
        s = fmaf(b_in[j] * D[j], W_out[(size_t)j * E_DIM + e], s);
    atomicAdd(&bo[e], s);
}

// ---------- shared 128x128 GEMM core: out[M,N] = A[M,K] @ Bt[N,K]^T (+bias) ----------
template <bool BIAS>
__device__ __forceinline__ void gemm128_core(bf16* lA, bf16* lB,
        const bf16* __restrict__ A, int lda, const bf16* __restrict__ Bt, int ldb,
        bf16* __restrict__ outp, int ldo, const float* __restrict__ bias, int K,
        int bn, int bm) {
    const int tid = threadIdx.x;
    const int lane = tid & 63, w = tid >> 6;
    const int wr = w >> 1, wc = w & 1;
    const int fr = lane & 15, fq = lane >> 4;
    f32x4 acc[4][4] = {};
    for (int k0 = 0; k0 < K; k0 += 32) {
#pragma unroll
        for (int L = 0; L < 2; ++L) {
            int idx = L * 256 + tid;
            int rr = idx >> 2, kk = (idx & 3) * 8;
            gload16(A + (size_t)(bm * 128 + rr) * lda + k0 + kk, lA + idx * 8);
            gload16(Bt + (size_t)(bn * 128 + rr) * ldb + k0 + kk, lB + idx * 8);
        }
        __syncthreads();
        bf16x8 af[4], bfr[4];
#pragma unroll
        for (int i = 0; i < 4; ++i)
            af[i] = *(const bf16x8*)(lA + (wr * 64 + i * 16 + fr) * 32 + fq * 8);
#pragma unroll
        for (int i = 0; i < 4; ++i)
            bfr[i] = *(const bf16x8*)(lB + (wc * 64 + i * 16 + fr) * 32 + fq * 8);
#pragma unroll
        for (int i = 0; i < 4; ++i)
#pragma unroll
            for (int j = 0; j < 4; ++j)
                acc[i][j] = __builtin_amdgcn_mfma_f32_16x16x32_bf16(af[i], bfr[j], acc[i][j], 0, 0, 0);
        __syncthreads();
    }
    const int orow = bm * 128 + wr * 64;
    const int ocol = bn * 128 + wc * 64;
#pragma unroll
    for (int i = 0; i < 4; ++i)
#pragma unroll
        for (int j = 0; j < 4; ++j) {
            int col = ocol + j * 16 + fr;
            float bv = BIAS ? bias[col] : 0.0f;
#pragma unroll
            for (int r = 0; r < 4; ++r) {
                int row = orow + i * 16 + fq * 4 + r;
                outp[(size_t)row * ldo + col] = __float2bfloat16(acc[i][j][r] + bv);
            }
        }
}

// ---------- G1: BuH[16384,2048] = xb @ WBcat^T + c_bu, XCD-swizzled ----------
__global__ __launch_bounds__(256)
void k_g1(const bf16* __restrict__ xb, const bf16* __restrict__ WBcat,
          bf16* __restrict__ BuH, const float* __restrict__ c_bu) {
    __shared__ __align__(16) bf16 lA[128 * 32];
    __shared__ __align__(16) bf16 lB[128 * 32];
    int id = blockIdx.x;                       // 2048, %8==0 -> bijective chunk swizzle
    int swz = (id & 7) * 256 + (id >> 3);
    int bn = swz & 15, bm = swz >> 4;          // per XCD: 16 bm-panels x all 16 bn
    gemm128_core<true>(lA, lB, xb, 512, WBcat, 512, BuH, 2048, c_bu, 512, bn, bm);
}

// ---------- batched small precompute GEMMs (one launch, 144 blocks) ----------
__global__ __launch_bounds__(256)
void k_gemm4(const bf16* __restrict__ BscT, const bf16* __restrict__ Win_b,
             const bf16* __restrict__ WoT, const bf16* __restrict__ WoTD,
             const bf16* __restrict__ Cr_b, const bf16* __restrict__ Ci_b,
             bf16* __restrict__ WBcat, bf16* __restrict__ Bfin) {
    __shared__ __align__(16) bf16 lA[128 * 32];
    __shared__ __align__(16) bf16 lB[128 * 32];
    int id = blockIdx.x;
    if (id < 64) {        // WBcat[2048,512] = BscT @ Win_b^T
        gemm128_core<false>(lA, lB, BscT, 1024, Win_b, 1024, WBcat, 512, nullptr, 1024, id & 3, id >> 2);
    } else if (id < 96) { // Bfin[:, 0:1024) = WoT @ Cr_b^T
        int l = id - 64;
        gemm128_core<false>(lA, lB, WoT, 1024, Cr_b, 1024, Bfin, 2560, nullptr, 1024, l & 7, l >> 3);
    } else if (id < 128) {// Bfin[:, 1024:2048) = WoT @ (-Ci)^T
        int l = id - 96;
        gemm128_core<false>(lA, lB, WoT, 1024, Ci_b, 1024, Bfin + 1024, 2560, nullptr, 1024, l & 7, l >> 3);
    } else {              // Bfin[:, 2048:2560) = WoTD @ Win_b^T
        int l = id - 128;
        gemm128_core<false>(lA, lB, WoTD, 1024, Win_b, 1024, Bfin + 2048, 2560, nullptr, 1024, l & 3, l >> 2);
    }
}

// ---------- G2: 512 threads, BM=128 x BN=256, single-buffer 2-barrier loop ----------
// 8 waves (2 wr x 4 wc), per-wave 64x64 output. Stage(t+1) issued between the
// two barriers so its L2/HBM latency hides under the MFMA cluster (m97 regime,
// now with 2 waves/SIMD instead of wide-N's 1).
template <bool ASPLIT>
__global__ __launch_bounds__(512)
void k_gemm_db(const bf16* __restrict__ A0, const bf16* __restrict__ A1, int ksplit,
               int lda0, int lda1, const bf16* __restrict__ Bt, int ldb,
               float* __restrict__ outp, int ldo, const float* __restrict__ bias, int K) {
    __shared__ __align__(16) bf16 lA[128 * 32];
    __shared__ __align__(16) bf16 lB[256 * 32];
    const int tid = threadIdx.x;
    int id = blockIdx.x;                       // 256 = 128 bm x 2 bn, %8==0 swizzle
    int swz = (id & 7) * 32 + (id >> 3);
    const int bm = swz >> 1, bn = swz & 1;
    const int lane = tid & 63, w = tid >> 6;
    const int wr = w >> 2, wc = w & 3;
    const int fr = lane & 15, fq = lane >> 4;
    f32x4 acc[4][4] = {};
    const int nt = K / 32;

    auto stage = [&](int t) {
        int k0 = t * 32;
        const bf16* Ap = A0; int lda = lda0, ac = k0;
        if (ASPLIT && k0 >= ksplit) { Ap = A1; lda = lda1; ac = k0 - ksplit; }
        {   // A: 128 rows x 32 cols, 512 x 16B loads, XOR-4 source pre-swizzle
            int rr = tid >> 2, s = tid & 3;
            int kk = (s ^ (rr & 3)) * 8;
            gload16(Ap + (size_t)(bm * 128 + rr) * lda + ac + kk, lA + tid * 8);
        }
#pragma unroll
        for (int L = 0; L < 2; ++L) {  // B: 256 rows x 32 cols, 1024 x 16B loads
            int idx = L * 512 + tid;
            int rr = idx >> 2, s = idx & 3;
            int kk = (s ^ (rr & 3)) * 8;
            gload16(Bt + (size_t)(bn * 256 + rr) * ldb + k0 + kk, lB + idx * 8);
        }
    };

    stage(0);
    for (int t = 0; t < nt; ++t) {
        __syncthreads();               // stage t complete (vmcnt0) + prev reads done
        bf16x8 af[4], bfr[4];
#pragma unroll
        for (int i = 0; i < 4; ++i) {
            int rr = wr * 64 + i * 16 + fr;
            af[i] = *(const bf16x8*)(lA + (rr * 4 + (fq ^ (rr & 3))) * 8);
        }
#pragma unroll
        for (int j = 0; j < 4; ++j) {
            int rr = wc * 64 + j * 16 + fr;
            bfr[j] = *(const bf16x8*)(lB + (rr * 4 + (fq ^ (rr & 3))) * 8);
        }
        __syncthreads();               // all waves done reading LDS (lgkm0)
        if (t + 1 < nt) stage(t + 1);  // overwrite LDS; completes by next bar
#pragma unroll
        for (int i = 0; i < 4; ++i)
#pragma unroll
            for (int j = 0; j < 4; ++j)
                acc[i][j] = __builtin_amdgcn_mfma_f32_16x16x32_bf16(af[i], bfr[j], acc[i][j], 0, 0, 0);
    }
    const int orow = bm * 128 + wr * 64;
    const int ocol = bn * 256 + wc * 64;
#pragma unroll
    for (int i = 0; i < 4; ++i)
#pragma unroll
        for (int j = 0; j < 4; ++j) {
            int col = ocol + j * 16 + fr;
            float bv = bias[col];
#pragma unroll
            for (int r = 0; r < 4; ++r)
                outp[(size_t)(orow + i * 16 + fq * 4 + r) * ldo + col] = acc[i][j][r] + bv;
        }
}

// ---------- chunked linear scan over time ----------
__global__ void k_scan_carry(const bf16* __restrict__ BuH, const float* __restrict__ LamR,
                             const float* __restrict__ LamI, float2* __restrict__ carry) {
    int tid = blockIdx.x * 256 + threadIdx.x;  // [0, NCHUNK*8192)
    int n = tid & (N_DIM - 1);
    int bb = (tid >> 10) & 7;
    int c = tid >> 13;
    float lr = LamR[n], li = LamI[n];
    float hr = 0.f, hi = 0.f;
    const bf16* p = BuH + ((size_t)(c * CLEN) * B_DIM + bb) * 2048 + n;
#pragma unroll 8
    for (int t = 0; t < CLEN; ++t) {
        float br = __bfloat162float(p[0]);
        float bi = __bfloat162float(p[N_DIM]);
        float nr = fmaf(lr, hr, fmaf(-li, hi, br));
        float ni = fmaf(lr, hi, fmaf(li, hr, bi));
        hr = nr; hi = ni;
        p += B_DIM * 2048;
    }
    carry[tid] = make_float2(hr, hi);
}

__global__ void k_scan_combine(const float2* __restrict__ carry, float2* __restrict__ S,
                               const float* __restrict__ LamR, const float* __restrict__ LamI) {
    int tid = blockIdx.x * 256 + threadIdx.x;  // [0, 8192)
    int n = tid & (N_DIM - 1);
    float ar = LamR[n], ai = LamI[n];
#pragma unroll
    for (int s = 0; s < 5; ++s) { float nr = ar * ar - ai * ai, ni = 2.f * ar * ai; ar = nr; ai = ni; }  // Lam^32
    float sr = 0.f, si = 0.f;
    for (int c = 0; c < NCHUNK; ++c) {
        S[(size_t)c * 8192 + tid] = make_float2(sr, si);
        float2 ca = carry[(size_t)c * 8192 + tid];
        float nr = fmaf(ar, sr, fmaf(-ai, si, ca.x));
        float ni = fmaf(ar, si, fmaf(ai, sr, ca.y));
        sr = nr; si = ni;
    }
}

__global__ void k_scan_apply(bf16* __restrict__ BuH, const float* __restrict__ LamR,
                             const float* __restrict__ LamI, const float2* __restrict__ S) {
    int tid = blockIdx.x * 256 + threadIdx.x;
    int n = tid & (N_DIM - 1);
    int bb = (tid >> 10) & 7;
    int c = tid >> 13;
    float lr = LamR[n], li = LamI[n];
    float2 s0 = S[tid];
    float hr = s0.x, hi = s0.y;
    bf16* p = BuH + ((size_t)(c * CLEN) * B_DIM + bb) * 2048 + n;
#pragma unroll 8
    for (int t = 0; t < CLEN; ++t) {
        float br = __bfloat162float(p[0]);
        float bi = __bfloat162float(p[N_DIM]);
        float nr = fmaf(lr, hr, fmaf(-li, hi, br));
        float ni = fmaf(lr, hi, fmaf(li, hr, bi));
        hr = nr; hi = ni;
        p[0] = __float2bfloat16(hr);
        p[N_DIM] = __float2bfloat16(hi);
        p += B_DIM * 2048;
    }
}

extern "C" void kernel_launch(void* const* d_in, const int* in_sizes, int n_in,
                              void* d_out, int out_size, void* d_ws, size_t ws_size,
                              hipStream_t stream) {
    const float* x         = (const float*)d_in[0];
    const float* W_in      = (const float*)d_in[1];
    const float* b_in      = (const float*)d_in[2];
    const float* W_out     = (const float*)d_in[3];
    const float* b_out     = (const float*)d_in[4];
    const float* nu_log    = (const float*)d_in[5];
    const float* theta_log = (const float*)d_in[6];
    const float* gamma_log = (const float*)d_in[7];
    const float* B_real    = (const float*)d_in[8];
    const float* B_imag    = (const float*)d_in[9];
    const float* C_real    = (const float*)d_in[10];
    const float* C_imag    = (const float*)d_in[11];
    const float* Dvec      = (const float*)d_in[12];
    float* out = (float*)d_out;

    char* ws = (char*)d_ws;
    size_t off = 0;
    auto alloc = [&](size_t bytes) { void* p = ws + off; off = (off + bytes + 255) & ~(size_t)255; return p; };
    bf16*  xb    = (bf16*)alloc((size_t)M_ROWS * E_DIM * 2);
    bf16*  BuH   = (bf16*)alloc((size_t)M_ROWS * 2048 * 2);
    bf16*  BscT  = (bf16*)alloc((size_t)2048 * 1024 * 2);
    bf16*  Win_b = (bf16*)alloc((size_t)512 * 1024 * 2);
    bf16*  Cr_b  = (bf16*)alloc((size_t)1024 * 1024 * 2);
    bf16*  Ci_b  = (bf16*)alloc((size_t)1024 * 1024 * 2);
    bf16*  WoT   = (bf16*)alloc((size_t)512 * 1024 * 2);
    bf16*  WoTD  = (bf16*)alloc((size_t)512 * 1024 * 2);
    bf16*  WBcat = (bf16*)alloc((size_t)2048 * 512 * 2);
    bf16*  Bfin  = (bf16*)alloc((size_t)512 * 2560 * 2);
    float* LamR  = (float*)alloc(1024 * 4);
    float* LamI  = (float*)alloc(1024 * 4);
    float* gvec  = (float*)alloc(1024 * 4);
    float* c_bu  = (float*)alloc(2048 * 4);
    float* biasO = (float*)alloc(512 * 4);
    float2* carry = (float2*)alloc((size_t)NCHUNK * 8192 * 8);
    float2* Sbuf  = (float2*)alloc((size_t)NCHUNK * 8192 * 8);

    // prep + converts
    k_prep<<<4, 256, 0, stream>>>(nu_log, theta_log, gamma_log, LamR, LamI, gvec);
    k_conv<<<2048, 256, 0, stream>>>(x, xb, M_ROWS * E_DIM / 4, 1.f);
    k_conv<<<512, 256, 0, stream>>>(W_in, Win_b, 512 * 1024 / 4, 1.f);
    k_conv<<<1024, 256, 0, stream>>>(C_real, Cr_b, 1024 * 1024 / 4, 1.f);
    k_conv<<<1024, 256, 0, stream>>>(C_imag, Ci_b, 1024 * 1024 / 4, -1.f);  // negated: -C_i
    k_transpose<<<dim3(32, 32), 256, 0, stream>>>(B_real, BscT, gvec, 1024, 1024);
    k_transpose<<<dim3(32, 32), 256, 0, stream>>>(B_imag, BscT + (size_t)1024 * 1024, gvec, 1024, 1024);
    k_transpose<<<dim3(16, 32), 256, 0, stream>>>(W_out, WoT, nullptr, 1024, 512);
    k_transpose<<<dim3(16, 32), 256, 0, stream>>>(W_out, WoTD, Dvec, 1024, 512);

    // bias vectors (zero first; ws is re-poisoned 0xAA before every call)
    hipMemsetAsync(c_bu, 0, 2048 * 4, stream);
    hipMemsetAsync(biasO, 0, 512 * 4, stream);
    k_bias_bu<<<64, 256, 0, stream>>>(b_in, gvec, B_real, B_imag, c_bu);
    k_bias_out<<<16, 256, 0, stream>>>(b_out, b_in, Dvec, W_out, biasO);

    // precompute folds: one batched launch (144 blocks)
    k_gemm4<<<144, 256, 0, stream>>>(BscT, Win_b, WoT, WoTD, Cr_b, Ci_b, WBcat, Bfin);

    // G1: BuH[16384,2048] = xb @ WBcat^T + c_bu   (Bu real|imag)
    k_g1<<<2048, 256, 0, stream>>>(xb, WBcat, BuH, c_bu);

    // scan: h_t = Lam*h_{t-1} + Bu_t  (in place, bf16 out)
    k_scan_carry<<<NCHUNK * 8192 / 256, 256, 0, stream>>>(BuH, LamR, LamI, carry);
    k_scan_combine<<<32, 256, 0, stream>>>(carry, Sbuf, LamR, LamI);
    k_scan_apply<<<NCHUNK * 8192 / 256, 256, 0, stream>>>(BuH, LamR, LamI, Sbuf);

    // G2: out[16384,512] = [h_r|h_i|xb] @ Bfin^T + biasO  (BM=128, BN=256, 512 thr)
    k_gemm_db<true><<<256, 512, 0, stream>>>(BuH, xb, 2048, 2048, 512, Bfin, 2560, out, 512, biasO, 2560);
}

// Round 10
// 339.245 us; speedup vs baseline: 1.4418x; 1.1155x over previous
//
#include <hip/hip_runtime.h>
#include <hip/hip_bf16.h>

typedef __hip_bfloat16 bf16;
typedef __attribute__((ext_vector_type(8))) short bf16x8;
typedef __attribute__((ext_vector_type(4))) float f32x4;

#define T_DIM 2048
#define B_DIM 8
#define E_DIM 512
#define N_DIM 1024
#define M_ROWS (T_DIM * B_DIM)   // 16384
#define NCHUNK 64
#define CLEN (T_DIM / NCHUNK)    // 32

__device__ __forceinline__ void gload16(const void* g, void* l) {
    __builtin_amdgcn_global_load_lds((const void __attribute__((address_space(1)))*)g,
                                     (void __attribute__((address_space(3)))*)l, 16, 0, 0);
}

// ---------- small prep: Lambda (complex), gamma ----------
__global__ void k_prep(const float* __restrict__ nu_log, const float* __restrict__ theta_log,
                       const float* __restrict__ gamma_log,
                       float* __restrict__ LamR, float* __restrict__ LamI, float* __restrict__ g) {
    int i = blockIdx.x * 256 + threadIdx.x;
    if (i < N_DIM) {
        float nu  = expf(nu_log[i]);
        float th  = expf(theta_log[i]);
        float mag = expf(-nu);
        LamR[i] = mag * cosf(th);
        LamI[i] = mag * sinf(th);
        g[i] = expf(gamma_log[i]);
    }
}

// ---------- merged fp32->bf16 converts: x, W_in, C_r, -C_i (one launch) ----------
// grid = 10752 = 8192 (x: 2,097,152 float4) + 512 (W_in) + 1024 (C_r) + 1024 (C_i)
struct __align__(8) bf4 { bf16 v[4]; };
__global__ void k_conv_all(const float* __restrict__ x, const float* __restrict__ W_in,
                           const float* __restrict__ C_r, const float* __restrict__ C_i,
                           bf16* __restrict__ xb, bf16* __restrict__ Win_b,
                           bf16* __restrict__ Cr_b, bf16* __restrict__ Ci_b) {
    int id = blockIdx.x;
    const float* src; bf16* dst; float mul = 1.f; int base;
    if (id < 8192)      { src = x;    dst = xb;    base = id; }
    else if (id < 8704) { src = W_in; dst = Win_b; base = id - 8192; }
    else if (id < 9728) { src = C_r;  dst = Cr_b;  base = id - 8704; }
    else                { src = C_i;  dst = Ci_b;  base = id - 9728; mul = -1.f; }
    int i = base * 256 + threadIdx.x;
    float4 v = ((const float4*)src)[i];
    bf4 o;
    o.v[0] = __float2bfloat16(v.x * mul);
    o.v[1] = __float2bfloat16(v.y * mul);
    o.v[2] = __float2bfloat16(v.z * mul);
    o.v[3] = __float2bfloat16(v.w * mul);
    ((bf4*)dst)[i] = o;
}

// ---------- merged transposes: B_r*g, B_i*g, W_out, W_out*D (one launch) ----------
__global__ void k_transpose_all(const float* __restrict__ B_r, const float* __restrict__ B_i,
                                const float* __restrict__ W_out, const float* __restrict__ gvec,
                                const float* __restrict__ Dvec,
                                bf16* __restrict__ BscT, bf16* __restrict__ WoT,
                                bf16* __restrict__ WoTD) {
    __shared__ float tile[32][33];
    int id = blockIdx.x;  // 3072 = 1024 + 1024 + 512 + 512
    const float* in; bf16* out; const float* scale; int R, C, bx, by;
    if (id < 1024)      { in = B_r;   out = BscT;                      scale = gvec; R = 1024; C = 1024; bx = id & 31;          by = id >> 5; }
    else if (id < 2048) { int l = id - 1024; in = B_i; out = BscT + (size_t)1024 * 1024; scale = gvec; R = 1024; C = 1024; bx = l & 31; by = l >> 5; }
    else if (id < 2560) { int l = id - 2048; in = W_out; out = WoT;    scale = nullptr; R = 1024; C = 512; bx = l & 15; by = l >> 4; }
    else                { int l = id - 2560; in = W_out; out = WoTD;   scale = Dvec;   R = 1024; C = 512; bx = l & 15; by = l >> 4; }
    int tx = threadIdx.x & 31, ty = threadIdx.x >> 5;
    int r0 = by * 32, c0 = bx * 32;
#pragma unroll
    for (int i = 0; i < 32; i += 8) {
        int r = r0 + ty + i;
        float v = in[(size_t)r * C + c0 + tx];
        if (scale) v *= scale[r];
        tile[ty + i][tx] = v;
    }
    __syncthreads();
#pragma unroll
    for (int i = 0; i < 32; i += 8) {
        out[(size_t)(c0 + ty + i) * R + r0 + tx] = __float2bfloat16(tile[tx][ty + i]);
    }
}

// ---------- bias vectors (K-chunk parallel + atomic reduce; buffers pre-zeroed) ----------
__global__ void k_bias_bu(const float* __restrict__ b_in, const float* __restrict__ g,
                          const float* __restrict__ B_real, const float* __restrict__ B_imag,
                          float* __restrict__ c_bu) {
    int id = blockIdx.x;              // 64 = 8 j-blocks x 8 i-chunks
    int jblk = id & 7, ic = id >> 3;
    int j = jblk * 256 + threadIdx.x; // 0..2047
    const float* B = (j < N_DIM) ? B_real : B_imag;
    int jj = j & (N_DIM - 1);
    float s = 0.f;
    for (int i = ic * 128; i < ic * 128 + 128; ++i)
        s = fmaf(b_in[i] * g[i], B[(size_t)i * N_DIM + jj], s);
    atomicAdd(&c_bu[j], s);
}

__global__ void k_bias_out(const float* __restrict__ b_out, const float* __restrict__ b_in,
                           const float* __restrict__ D, const float* __restrict__ W_out,
                           float* __restrict__ bo) {
    int id = blockIdx.x;              // 16 = 2 e-blocks x 8 j-chunks
    int eblk = id & 1, ic = id >> 1;
    int e = eblk * 256 + threadIdx.x;
    float s = (ic == 0) ? b_out[e] : 0.f;
    for (int j = ic * 128; j < ic * 128 + 128; ++j)
        s = fmaf(b_in[j] * D[j], W_out[(size_t)j * E_DIM + e], s);
    atomicAdd(&bo[e], s);
}

// ---------- shared 128x128 GEMM core, T3-minimum double-buffer ----------
// Per K-step: STAGE(buf^1, t+1) -> ds_read buf -> setprio(1) MFMA setprio(0)
// -> ONE __syncthreads (drains vmcnt: stage done; lgkm: reads done).
// lds layout: [buf][A 128x32 | B 128x32], XOR-4 slot swizzle on source + read.
template <bool ASPLIT, bool OUTF32, bool BIAS>
__device__ __forceinline__ void gemm_db_core(bf16* lds,
        const bf16* __restrict__ A0, const bf16* __restrict__ A1, int ksplit,
        int lda0, int lda1, const bf16* __restrict__ Bt, int ldb,
        void* __restrict__ outp, int ldo, const float* __restrict__ bias, int K,
        int bn, int bm) {
    const int tid = threadIdx.x;
    const int lane = tid & 63, w = tid >> 6;
    const int wr = w >> 1, wc = w & 1;
    const int fr = lane & 15, fq = lane >> 4;
    f32x4 acc[4][4] = {};
    const int nt = K / 32;

    auto stage = [&](int buf, int t) {
        int k0 = t * 32;
        const bf16* Ap = A0; int lda = lda0, ac = k0;
        if (ASPLIT && k0 >= ksplit) { Ap = A1; lda = lda1; ac = k0 - ksplit; }
        bf16* dst = lds + buf * 8192;
#pragma unroll
        for (int L = 0; L < 2; ++L) {
            int idx = L * 256 + tid;
            int rr = idx >> 2, s = idx & 3;
            int kk = (s ^ (rr & 3)) * 8;   // involution src pre-swizzle
            gload16(Ap + (size_t)(bm * 128 + rr) * lda + ac + kk, dst + idx * 8);
            gload16(Bt + (size_t)(bn * 128 + rr) * ldb + k0 + kk, dst + 4096 + idx * 8);
        }
    };

    stage(0, 0);
    __syncthreads();
    int cur = 0;
    for (int t = 0; t < nt; ++t) {
        if (t + 1 < nt) stage(cur ^ 1, t + 1);     // issue next-tile loads first
        const bf16* bufA = lds + cur * 8192;
        const bf16* bufB = bufA + 4096;
        bf16x8 af[4], bfr[4];
#pragma unroll
        for (int i = 0; i < 4; ++i) {
            int rr = wr * 64 + i * 16 + fr;
            af[i] = *(const bf16x8*)(bufA + (rr * 4 + (fq ^ (rr & 3))) * 8);
        }
#pragma unroll
        for (int j = 0; j < 4; ++j) {
            int rr = wc * 64 + j * 16 + fr;
            bfr[j] = *(const bf16x8*)(bufB + (rr * 4 + (fq ^ (rr & 3))) * 8);
        }
        __builtin_amdgcn_s_setprio(1);
#pragma unroll
        for (int i = 0; i < 4; ++i)
#pragma unroll
            for (int j = 0; j < 4; ++j)
                acc[i][j] = __builtin_amdgcn_mfma_f32_16x16x32_bf16(af[i], bfr[j], acc[i][j], 0, 0, 0);
        __builtin_amdgcn_s_setprio(0);
        __syncthreads();                            // stage(t+1) complete + reads done
        cur ^= 1;
    }
    const int orow = bm * 128 + wr * 64;
    const int ocol = bn * 128 + wc * 64;
#pragma unroll
    for (int i = 0; i < 4; ++i)
#pragma unroll
        for (int j = 0; j < 4; ++j) {
            int col = ocol + j * 16 + fr;
            float bv = BIAS ? bias[col] : 0.0f;
#pragma unroll
            for (int r = 0; r < 4; ++r) {
                int row = orow + i * 16 + fq * 4 + r;
                float v = acc[i][j][r] + bv;
                if (OUTF32) ((float*)outp)[(size_t)row * ldo + col] = v;
                else        ((bf16*)outp)[(size_t)row * ldo + col] = __float2bfloat16(v);
            }
        }
}

// ---------- G1: BuH[16384,2048] = xb @ WBcat^T + c_bu, XCD-swizzled ----------
__global__ __launch_bounds__(256)
void k_g1(const bf16* __restrict__ xb, const bf16* __restrict__ WBcat,
          bf16* __restrict__ BuH, const float* __restrict__ c_bu) {
    __shared__ __align__(16) bf16 lds[2 * 8192];
    int id = blockIdx.x;                       // 2048, %8==0 -> bijective chunk swizzle
    int swz = (id & 7) * 256 + (id >> 3);
    int bn = swz & 15, bm = swz >> 4;
    gemm_db_core<false, false, true>(lds, xb, nullptr, 0, 512, 0, WBcat, 512,
                                     BuH, 2048, c_bu, 512, bn, bm);
}

// ---------- G2: out[16384,512] = [h_r|h_i|xb] @ Bfin^T + biasO ----------
__global__ __launch_bounds__(256)
void k_g2(const bf16* __restrict__ BuH, const bf16* __restrict__ xb,
          const bf16* __restrict__ Bfin, float* __restrict__ out,
          const float* __restrict__ biasO) {
    __shared__ __align__(16) bf16 lds[2 * 8192];
    int id = blockIdx.x;                       // 512 = 128 bm x 4 bn, %8==0 swizzle
    int swz = (id & 7) * 64 + (id >> 3);
    int bn = swz & 3, bm = swz >> 2;
    gemm_db_core<true, true, true>(lds, BuH, xb, 2048, 2048, 512, Bfin, 2560,
                                   out, 512, biasO, 2560, bn, bm);
}

// ---------- batched small precompute GEMMs (one launch, 144 blocks) ----------
__global__ __launch_bounds__(256)
void k_gemm4(const bf16* __restrict__ BscT, const bf16* __restrict__ Win_b,
             const bf16* __restrict__ WoT, const bf16* __restrict__ WoTD,
             const bf16* __restrict__ Cr_b, const bf16* __restrict__ Ci_b,
             bf16* __restrict__ WBcat, bf16* __restrict__ Bfin) {
    __shared__ __align__(16) bf16 lds[2 * 8192];
    int id = blockIdx.x;
    if (id < 64) {        // WBcat[2048,512] = BscT @ Win_b^T
        gemm_db_core<false, false, false>(lds, BscT, nullptr, 0, 1024, 0, Win_b, 1024, WBcat, 512, nullptr, 1024, id & 3, id >> 2);
    } else if (id < 96) { // Bfin[:, 0:1024) = WoT @ Cr_b^T
        int l = id - 64;
        gemm_db_core<false, false, false>(lds, WoT, nullptr, 0, 1024, 0, Cr_b, 1024, Bfin, 2560, nullptr, 1024, l & 7, l >> 3);
    } else if (id < 128) {// Bfin[:, 1024:2048) = WoT @ (-Ci)^T
        int l = id - 96;
        gemm_db_core<false, false, false>(lds, WoT, nullptr, 0, 1024, 0, Ci_b, 1024, Bfin + 1024, 2560, nullptr, 1024, l & 7, l >> 3);
    } else {              // Bfin[:, 2048:2560) = WoTD @ Win_b^T
        int l = id - 128;
        gemm_db_core<false, false, false>(lds, WoTD, nullptr, 0, 1024, 0, Win_b, 1024, Bfin + 2048, 2560, nullptr, 1024, l & 3, l >> 2);
    }
}

// ---------- chunked linear scan over time ----------
__global__ void k_scan_carry(const bf16* __restrict__ BuH, const float* __restrict__ LamR,
                             const float* __restrict__ LamI, float2* __restrict__ carry) {
    int tid = blockIdx.x * 256 + threadIdx.x;  // [0, NCHUNK*8192)
    int n = tid & (N_DIM - 1);
    int bb = (tid >> 10) & 7;
    int c = tid >> 13;
    float lr = LamR[n], li = LamI[n];
    float hr = 0.f, hi = 0.f;
    const bf16* p = BuH + ((size_t)(c * CLEN) * B_DIM + bb) * 2048 + n;
#pragma unroll 8
    for (int t = 0; t < CLEN; ++t) {
        float br = __bfloat162float(p[0]);
        float bi = __bfloat162float(p[N_DIM]);
        float nr = fmaf(lr, hr, fmaf(-li, hi, br));
        float ni = fmaf(lr, hi, fmaf(li, hr, bi));
        hr = nr; hi = ni;
        p += B_DIM * 2048;
    }
    carry[tid] = make_float2(hr, hi);
}

__global__ void k_scan_combine(const float2* __restrict__ carry, float2* __restrict__ S,
                               const float* __restrict__ LamR, const float* __restrict__ LamI) {
    int tid = blockIdx.x * 256 + threadIdx.x;  // [0, 8192)
    int n = tid & (N_DIM - 1);
    float ar = LamR[n], ai = LamI[n];
#pragma unroll
    for (int s = 0; s < 5; ++s) { float nr = ar * ar - ai * ai, ni = 2.f * ar * ai; ar = nr; ai = ni; }  // Lam^32
    float sr = 0.f, si = 0.f;
    for (int c = 0; c < NCHUNK; ++c) {
        S[(size_t)c * 8192 + tid] = make_float2(sr, si);
        float2 ca = carry[(size_t)c * 8192 + tid];
        float nr = fmaf(ar, sr, fmaf(-ai, si, ca.x));
        float ni = fmaf(ar, si, fmaf(ai, sr, ca.y));
        sr = nr; si = ni;
    }
}

__global__ void k_scan_apply(bf16* __restrict__ BuH, const float* __restrict__ LamR,
                             const float* __restrict__ LamI, const float2* __restrict__ S) {
    int tid = blockIdx.x * 256 + threadIdx.x;
    int n = tid & (N_DIM - 1);
    int bb = (tid >> 10) & 7;
    int c = tid >> 13;
    float lr = LamR[n], li = LamI[n];
    float2 s0 = S[tid];
    float hr = s0.x, hi = s0.y;
    bf16* p = BuH + ((size_t)(c * CLEN) * B_DIM + bb) * 2048 + n;
#pragma unroll 8
    for (int t = 0; t < CLEN; ++t) {
        float br = __bfloat162float(p[0]);
        float bi = __bfloat162float(p[N_DIM]);
        float nr = fmaf(lr, hr, fmaf(-li, hi, br));
        float ni = fmaf(lr, hi, fmaf(li, hr, bi));
        hr = nr; hi = ni;
        p[0] = __float2bfloat16(hr);
        p[N_DIM] = __float2bfloat16(hi);
        p += B_DIM * 2048;
    }
}

extern "C" void kernel_launch(void* const* d_in, const int* in_sizes, int n_in,
                              void* d_out, int out_size, void* d_ws, size_t ws_size,
                              hipStream_t stream) {
    const float* x         = (const float*)d_in[0];
    const float* W_in      = (const float*)d_in[1];
    const float* b_in      = (const float*)d_in[2];
    const float* W_out     = (const float*)d_in[3];
    const float* b_out     = (const float*)d_in[4];
    const float* nu_log    = (const float*)d_in[5];
    const float* theta_log = (const float*)d_in[6];
    const float* gamma_log = (const float*)d_in[7];
    const float* B_real    = (const float*)d_in[8];
    const float* B_imag    = (const float*)d_in[9];
    const float* C_real    = (const float*)d_in[10];
    const float* C_imag    = (const float*)d_in[11];
    const float* Dvec      = (const float*)d_in[12];
    float* out = (float*)d_out;

    char* ws = (char*)d_ws;
    size_t off = 0;
    auto alloc = [&](size_t bytes) { void* p = ws + off; off = (off + bytes + 255) & ~(size_t)255; return p; };
    bf16*  xb    = (bf16*)alloc((size_t)M_ROWS * E_DIM * 2);
    bf16*  BuH   = (bf16*)alloc((size_t)M_ROWS * 2048 * 2);
    bf16*  BscT  = (bf16*)alloc((size_t)2048 * 1024 * 2);
    bf16*  Win_b = (bf16*)alloc((size_t)512 * 1024 * 2);
    bf16*  Cr_b  = (bf16*)alloc((size_t)1024 * 1024 * 2);
    bf16*  Ci_b  = (bf16*)alloc((size_t)1024 * 1024 * 2);
    bf16*  WoT   = (bf16*)alloc((size_t)512 * 1024 * 2);
    bf16*  WoTD  = (bf16*)alloc((size_t)512 * 1024 * 2);
    bf16*  WBcat = (bf16*)alloc((size_t)2048 * 512 * 2);
    bf16*  Bfin  = (bf16*)alloc((size_t)512 * 2560 * 2);
    float* LamR  = (float*)alloc(1024 * 4);
    float* LamI  = (float*)alloc(1024 * 4);
    float* gvec  = (float*)alloc(1024 * 4);
    float* c_bu  = (float*)alloc(2048 * 4);
    float* biasO = (float*)alloc(512 * 4);
    float2* carry = (float2*)alloc((size_t)NCHUNK * 8192 * 8);
    float2* Sbuf  = (float2*)alloc((size_t)NCHUNK * 8192 * 8);

    // prep + merged converts/transposes
    k_prep<<<4, 256, 0, stream>>>(nu_log, theta_log, gamma_log, LamR, LamI, gvec);
    k_conv_all<<<10752, 256, 0, stream>>>(x, W_in, C_real, C_imag, xb, Win_b, Cr_b, Ci_b);
    k_transpose_all<<<3072, 256, 0, stream>>>(B_real, B_imag, W_out, gvec, Dvec, BscT, WoT, WoTD);

    // bias vectors (zero first; ws is re-poisoned 0xAA before every call)
    hipMemsetAsync(c_bu, 0, 2048 * 4, stream);
    hipMemsetAsync(biasO, 0, 512 * 4, stream);
    k_bias_bu<<<64, 256, 0, stream>>>(b_in, gvec, B_real, B_imag, c_bu);
    k_bias_out<<<16, 256, 0, stream>>>(b_out, b_in, Dvec, W_out, biasO);

    // precompute folds: one batched launch (144 blocks)
    k_gemm4<<<144, 256, 0, stream>>>(BscT, Win_b, WoT, WoTD, Cr_b, Ci_b, WBcat, Bfin);

    // G1: BuH[16384,2048] = xb @ WBcat^T + c_bu   (Bu real|imag)
    k_g1<<<2048, 256, 0, stream>>>(xb, WBcat, BuH, c_bu);

    // scan: h_t = Lam*h_{t-1} + Bu_t  (in place, bf16 out)
    k_scan_carry<<<NCHUNK * 8192 / 256, 256, 0, stream>>>(BuH, LamR, LamI, carry);
    k_scan_combine<<<32, 256, 0, stream>>>(carry, Sbuf, LamR, LamI);
    k_scan_apply<<<NCHUNK * 8192 / 256, 256, 0, stream>>>(BuH, LamR, LamI, Sbuf);

    // G2: out[16384,512] = [h_r|h_i|xb] @ Bfin^T + biasO
    k_g2<<<512, 256, 0, stream>>>(BuH, xb, Bfin, out, biasO);
}

// Round 11
// 334.189 us; speedup vs baseline: 1.4636x; 1.0151x over previous
//
#include <hip/hip_runtime.h>
#include <hip/hip_bf16.h>

typedef __hip_bfloat16 bf16;
typedef __attribute__((ext_vector_type(8))) short bf16x8;
typedef __attribute__((ext_vector_type(4))) float f32x4;

#define T_DIM 2048
#define B_DIM 8
#define E_DIM 512
#define N_DIM 1024
#define M_ROWS (T_DIM * B_DIM)   // 16384
#define NCHUNK 64
#define CLEN (T_DIM / NCHUNK)    // 32

__device__ __forceinline__ void gload16(const void* g, void* l) {
    __builtin_amdgcn_global_load_lds((const void __attribute__((address_space(1)))*)g,
                                     (void __attribute__((address_space(3)))*)l, 16, 0, 0);
}

// ---------- small prep: Lambda (complex), gamma ----------
__global__ void k_prep(const float* __restrict__ nu_log, const float* __restrict__ theta_log,
                       const float* __restrict__ gamma_log,
                       float* __restrict__ LamR, float* __restrict__ LamI, float* __restrict__ g) {
    int i = blockIdx.x * 256 + threadIdx.x;
    if (i < N_DIM) {
        float nu  = expf(nu_log[i]);
        float th  = expf(theta_log[i]);
        float mag = expf(-nu);
        LamR[i] = mag * cosf(th);
        LamI[i] = mag * sinf(th);
        g[i] = expf(gamma_log[i]);
    }
}

// ---------- merged fp32->bf16 converts: x, W_in, C_r, -C_i (one launch) ----------
// grid = 10752 = 8192 (x: 2,097,152 float4) + 512 (W_in) + 1024 (C_r) + 1024 (C_i)
struct __align__(8) bf4 { bf16 v[4]; };
__global__ void k_conv_all(const float* __restrict__ x, const float* __restrict__ W_in,
                           const float* __restrict__ C_r, const float* __restrict__ C_i,
                           bf16* __restrict__ xb, bf16* __restrict__ Win_b,
                           bf16* __restrict__ Cr_b, bf16* __restrict__ Ci_b) {
    int id = blockIdx.x;
    const float* src; bf16* dst; float mul = 1.f; int base;
    if (id < 8192)      { src = x;    dst = xb;    base = id; }
    else if (id < 8704) { src = W_in; dst = Win_b; base = id - 8192; }
    else if (id < 9728) { src = C_r;  dst = Cr_b;  base = id - 8704; }
    else                { src = C_i;  dst = Ci_b;  base = id - 9728; mul = -1.f; }
    int i = base * 256 + threadIdx.x;
    float4 v = ((const float4*)src)[i];
    bf4 o;
    o.v[0] = __float2bfloat16(v.x * mul);
    o.v[1] = __float2bfloat16(v.y * mul);
    o.v[2] = __float2bfloat16(v.z * mul);
    o.v[3] = __float2bfloat16(v.w * mul);
    ((bf4*)dst)[i] = o;
}

// ---------- merged transposes: B_r*g, B_i*g, W_out, W_out*D (one launch) ----------
__global__ void k_transpose_all(const float* __restrict__ B_r, const float* __restrict__ B_i,
                                const float* __restrict__ W_out, const float* __restrict__ gvec,
                                const float* __restrict__ Dvec,
                                bf16* __restrict__ BscT, bf16* __restrict__ WoT,
                                bf16* __restrict__ WoTD) {
    __shared__ float tile[32][33];
    int id = blockIdx.x;  // 3072 = 1024 + 1024 + 512 + 512
    const float* in; bf16* out; const float* scale; int R, C, bx, by;
    if (id < 1024)      { in = B_r;   out = BscT;                      scale = gvec; R = 1024; C = 1024; bx = id & 31;          by = id >> 5; }
    else if (id < 2048) { int l = id - 1024; in = B_i; out = BscT + (size_t)1024 * 1024; scale = gvec; R = 1024; C = 1024; bx = l & 31; by = l >> 5; }
    else if (id < 2560) { int l = id - 2048; in = W_out; out = WoT;    scale = nullptr; R = 1024; C = 512; bx = l & 15; by = l >> 4; }
    else                { int l = id - 2560; in = W_out; out = WoTD;   scale = Dvec;   R = 1024; C = 512; bx = l & 15; by = l >> 4; }
    int tx = threadIdx.x & 31, ty = threadIdx.x >> 5;
    int r0 = by * 32, c0 = bx * 32;
#pragma unroll
    for (int i = 0; i < 32; i += 8) {
        int r = r0 + ty + i;
        float v = in[(size_t)r * C + c0 + tx];
        if (scale) v *= scale[r];
        tile[ty + i][tx] = v;
    }
    __syncthreads();
#pragma unroll
    for (int i = 0; i < 32; i += 8) {
        out[(size_t)(c0 + ty + i) * R + r0 + tx] = __float2bfloat16(tile[tx][ty + i]);
    }
}

// ---------- bias vectors (K-chunk parallel + atomic reduce; buffers pre-zeroed) ----------
__global__ void k_bias_bu(const float* __restrict__ b_in, const float* __restrict__ g,
                          const float* __restrict__ B_real, const float* __restrict__ B_imag,
                          float* __restrict__ c_bu) {
    int id = blockIdx.x;              // 64 = 8 j-blocks x 8 i-chunks
    int jblk = id & 7, ic = id >> 3;
    int j = jblk * 256 + threadIdx.x; // 0..2047
    const float* B = (j < N_DIM) ? B_real : B_imag;
    int jj = j & (N_DIM - 1);
    float s = 0.f;
    for (int i = ic * 128; i < ic * 128 + 128; ++i)
        s = fmaf(b_in[i] * g[i], B[(size_t)i * N_DIM + jj], s);
    atomicAdd(&c_bu[j], s);
}

__global__ void k_bias_out(const float* __restrict__ b_out, const float* __restrict__ b_in,
                           const float* __restrict__ D, const float* __restrict__ W_out,
                           float* __restrict__ bo) {
    int id = blockIdx.x;              // 16 = 2 e-blocks x 8 j-chunks
    int eblk = id & 1, ic = id >> 1;
    int e = eblk * 256 + threadIdx.x;
    float s = (ic == 0) ? b_out[e] : 0.f;
    for (int j = ic * 128; j < ic * 128 + 128; ++j)
        s = fmaf(b_in[j] * D[j], W_out[(size_t)j * E_DIM + e], s);
    atomicAdd(&bo[e], s);
}

// ---------- shared 128x128 GEMM core, TRIPLE-buffer + counted vmcnt (T3+T4) ----------
// Iter t: {vmcnt(4) [stage(t) done, stage(t+1) in flight] ; lgkmcnt(0) [my t-1
// reads done] ; raw s_barrier ; stage(t+2)->buf[(t+2)%3] ; ds_read buf[t%3] ;
// setprio(1) MFMA setprio(0)}. One barrier/iter, loads stay in flight across it.
// Hazards: read-ready = own vmcnt(4)+barrier (collective); overwrite target
// buf[(t+2)%3] was read at t-1, protected by lgkmcnt(0)-before-barrier.
template <bool ASPLIT, bool OUTF32, bool BIAS>
__device__ __forceinline__ void gemm_tb_core(bf16* lds,
        const bf16* __restrict__ A0, const bf16* __restrict__ A1, int ksplit,
        int lda0, int lda1, const bf16* __restrict__ Bt, int ldb,
        void* __restrict__ outp, int ldo, const float* __restrict__ bias, int K,
        int bn, int bm) {
    const int tid = threadIdx.x;
    const int lane = tid & 63, w = tid >> 6;
    const int wr = w >> 1, wc = w & 1;
    const int fr = lane & 15, fq = lane >> 4;
    f32x4 acc[4][4] = {};
    const int nt = K / 32;

    auto stage = [&](int buf, int t) {   // 4 gload16 per thread per stage
        int k0 = t * 32;
        const bf16* Ap = A0; int lda = lda0, ac = k0;
        if (ASPLIT && k0 >= ksplit) { Ap = A1; lda = lda1; ac = k0 - ksplit; }
        bf16* dst = lds + buf * 8192;
#pragma unroll
        for (int L = 0; L < 2; ++L) {
            int idx = L * 256 + tid;
            int rr = idx >> 2, s = idx & 3;
            int kk = (s ^ (rr & 3)) * 8;   // involution src pre-swizzle
            gload16(Ap + (size_t)(bm * 128 + rr) * lda + ac + kk, dst + idx * 8);
            gload16(Bt + (size_t)(bn * 128 + rr) * ldb + k0 + kk, dst + 4096 + idx * 8);
        }
    };

    stage(0, 0);
    stage(1, 1);
    int cur = 0;                          // buffer holding K-tile t
    for (int t = 0; t < nt; ++t) {
        if (t < nt - 1) asm volatile("s_waitcnt vmcnt(4)" ::: "memory");
        else            asm volatile("s_waitcnt vmcnt(0)" ::: "memory");
        asm volatile("s_waitcnt lgkmcnt(0)" ::: "memory");
        __builtin_amdgcn_s_barrier();
        __builtin_amdgcn_sched_barrier(0);
        if (t + 2 < nt) stage(cur == 0 ? 2 : cur - 1, t + 2);  // (t+2)%3
        const bf16* bufA = lds + cur * 8192;
        const bf16* bufB = bufA + 4096;
        bf16x8 af[4], bfr[4];
#pragma unroll
        for (int i = 0; i < 4; ++i) {
            int rr = wr * 64 + i * 16 + fr;
            af[i] = *(const bf16x8*)(bufA + (rr * 4 + (fq ^ (rr & 3))) * 8);
        }
#pragma unroll
        for (int j = 0; j < 4; ++j) {
            int rr = wc * 64 + j * 16 + fr;
            bfr[j] = *(const bf16x8*)(bufB + (rr * 4 + (fq ^ (rr & 3))) * 8);
        }
        __builtin_amdgcn_s_setprio(1);
#pragma unroll
        for (int i = 0; i < 4; ++i)
#pragma unroll
            for (int j = 0; j < 4; ++j)
                acc[i][j] = __builtin_amdgcn_mfma_f32_16x16x32_bf16(af[i], bfr[j], acc[i][j], 0, 0, 0);
        __builtin_amdgcn_s_setprio(0);
        cur = (cur == 2) ? 0 : cur + 1;
    }
    const int orow = bm * 128 + wr * 64;
    const int ocol = bn * 128 + wc * 64;
#pragma unroll
    for (int i = 0; i < 4; ++i)
#pragma unroll
        for (int j = 0; j < 4; ++j) {
            int col = ocol + j * 16 + fr;
            float bv = BIAS ? bias[col] : 0.0f;
#pragma unroll
            for (int r = 0; r < 4; ++r) {
                int row = orow + i * 16 + fq * 4 + r;
                float v = acc[i][j][r] + bv;
                if (OUTF32) ((float*)outp)[(size_t)row * ldo + col] = v;
                else        ((bf16*)outp)[(size_t)row * ldo + col] = __float2bfloat16(v);
            }
        }
}

// ---------- G1: BuH[16384,2048] = xb @ WBcat^T + c_bu, XCD-swizzled ----------
__global__ __launch_bounds__(256)
void k_g1(const bf16* __restrict__ xb, const bf16* __restrict__ WBcat,
          bf16* __restrict__ BuH, const float* __restrict__ c_bu) {
    __shared__ __align__(16) bf16 lds[3 * 8192];
    int id = blockIdx.x;                       // 2048, %8==0 -> bijective chunk swizzle
    int swz = (id & 7) * 256 + (id >> 3);
    int bn = swz & 15, bm = swz >> 4;
    gemm_tb_core<false, false, true>(lds, xb, nullptr, 0, 512, 0, WBcat, 512,
                                     BuH, 2048, c_bu, 512, bn, bm);
}

// ---------- G2: out[16384,512] = [h_r|h_i|xb] @ Bfin^T + biasO ----------
__global__ __launch_bounds__(256)
void k_g2(const bf16* __restrict__ BuH, const bf16* __restrict__ xb,
          const bf16* __restrict__ Bfin, float* __restrict__ out,
          const float* __restrict__ biasO) {
    __shared__ __align__(16) bf16 lds[3 * 8192];
    int id = blockIdx.x;                       // 512 = 128 bm x 4 bn, %8==0 swizzle
    int swz = (id & 7) * 64 + (id >> 3);
    int bn = swz & 3, bm = swz >> 2;
    gemm_tb_core<true, true, true>(lds, BuH, xb, 2048, 2048, 512, Bfin, 2560,
                                   out, 512, biasO, 2560, bn, bm);
}

// ---------- batched small precompute GEMMs (one launch, 144 blocks) ----------
__global__ __launch_bounds__(256)
void k_gemm4(const bf16* __restrict__ BscT, const bf16* __restrict__ Win_b,
             const bf16* __restrict__ WoT, const bf16* __restrict__ WoTD,
             const bf16* __restrict__ Cr_b, const bf16* __restrict__ Ci_b,
             bf16* __restrict__ WBcat, bf16* __restrict__ Bfin) {
    __shared__ __align__(16) bf16 lds[3 * 8192];
    int id = blockIdx.x;
    if (id < 64) {        // WBcat[2048,512] = BscT @ Win_b^T
        gemm_tb_core<false, false, false>(lds, BscT, nullptr, 0, 1024, 0, Win_b, 1024, WBcat, 512, nullptr, 1024, id & 3, id >> 2);
    } else if (id < 96) { // Bfin[:, 0:1024) = WoT @ Cr_b^T
        int l = id - 64;
        gemm_tb_core<false, false, false>(lds, WoT, nullptr, 0, 1024, 0, Cr_b, 1024, Bfin, 2560, nullptr, 1024, l & 7, l >> 3);
    } else if (id < 128) {// Bfin[:, 1024:2048) = WoT @ (-Ci)^T
        int l = id - 96;
        gemm_tb_core<false, false, false>(lds, WoT, nullptr, 0, 1024, 0, Ci_b, 1024, Bfin + 1024, 2560, nullptr, 1024, l & 7, l >> 3);
    } else {              // Bfin[:, 2048:2560) = WoTD @ Win_b^T
        int l = id - 128;
        gemm_tb_core<false, false, false>(lds, WoTD, nullptr, 0, 1024, 0, Win_b, 1024, Bfin + 2048, 2560, nullptr, 1024, l & 3, l >> 2);
    }
}

// ---------- chunked linear scan over time ----------
__global__ void k_scan_carry(const bf16* __restrict__ BuH, const float* __restrict__ LamR,
                             const float* __restrict__ LamI, float2* __restrict__ carry) {
    int tid = blockIdx.x * 256 + threadIdx.x;  // [0, NCHUNK*8192)
    int n = tid & (N_DIM - 1);
    int bb = (tid >> 10) & 7;
    int c = tid >> 13;
    float lr = LamR[n], li = LamI[n];
    float hr = 0.f, hi = 0.f;
    const bf16* p = BuH + ((size_t)(c * CLEN) * B_DIM + bb) * 2048 + n;
#pragma unroll 8
    for (int t = 0; t < CLEN; ++t) {
        float br = __bfloat162float(p[0]);
        float bi = __bfloat162float(p[N_DIM]);
        float nr = fmaf(lr, hr, fmaf(-li, hi, br));
        float ni = fmaf(lr, hi, fmaf(li, hr, bi));
        hr = nr; hi = ni;
        p += B_DIM * 2048;
    }
    carry[tid] = make_float2(hr, hi);
}

__global__ void k_scan_combine(const float2* __restrict__ carry, float2* __restrict__ S,
                               const float* __restrict__ LamR, const float* __restrict__ LamI) {
    int tid = blockIdx.x * 256 + threadIdx.x;  // [0, 8192)
    int n = tid & (N_DIM - 1);
    float ar = LamR[n], ai = LamI[n];
#pragma unroll
    for (int s = 0; s < 5; ++s) { float nr = ar * ar - ai * ai, ni = 2.f * ar * ai; ar = nr; ai = ni; }  // Lam^32
    float sr = 0.f, si = 0.f;
    for (int c = 0; c < NCHUNK; ++c) {
        S[(size_t)c * 8192 + tid] = make_float2(sr, si);
        float2 ca = carry[(size_t)c * 8192 + tid];
        float nr = fmaf(ar, sr, fmaf(-ai, si, ca.x));
        float ni = fmaf(ar, si, fmaf(ai, sr, ca.y));
        sr = nr; si = ni;
    }
}

__global__ void k_scan_apply(bf16* __restrict__ BuH, const float* __restrict__ LamR,
                             const float* __restrict__ LamI, const float2* __restrict__ S) {
    int tid = blockIdx.x * 256 + threadIdx.x;
    int n = tid & (N_DIM - 1);
    int bb = (tid >> 10) & 7;
    int c = tid >> 13;
    float lr = LamR[n], li = LamI[n];
    float2 s0 = S[tid];
    float hr = s0.x, hi = s0.y;
    bf16* p = BuH + ((size_t)(c * CLEN) * B_DIM + bb) * 2048 + n;
#pragma unroll 8
    for (int t = 0; t < CLEN; ++t) {
        float br = __bfloat162float(p[0]);
        float bi = __bfloat162float(p[N_DIM]);
        float nr = fmaf(lr, hr, fmaf(-li, hi, br));
        float ni = fmaf(lr, hi, fmaf(li, hr, bi));
        hr = nr; hi = ni;
        p[0] = __float2bfloat16(hr);
        p[N_DIM] = __float2bfloat16(hi);
        p += B_DIM * 2048;
    }
}

extern "C" void kernel_launch(void* const* d_in, const int* in_sizes, int n_in,
                              void* d_out, int out_size, void* d_ws, size_t ws_size,
                              hipStream_t stream) {
    const float* x         = (const float*)d_in[0];
    const float* W_in      = (const float*)d_in[1];
    const float* b_in      = (const float*)d_in[2];
    const float* W_out     = (const float*)d_in[3];
    const float* b_out     = (const float*)d_in[4];
    const float* nu_log    = (const float*)d_in[5];
    const float* theta_log = (const float*)d_in[6];
    const float* gamma_log = (const float*)d_in[7];
    const float* B_real    = (const float*)d_in[8];
    const float* B_imag    = (const float*)d_in[9];
    const float* C_real    = (const float*)d_in[10];
    const float* C_imag    = (const float*)d_in[11];
    const float* Dvec      = (const float*)d_in[12];
    float* out = (float*)d_out;

    char* ws = (char*)d_ws;
    size_t off = 0;
    auto alloc = [&](size_t bytes) { void* p = ws + off; off = (off + bytes + 255) & ~(size_t)255; return p; };
    bf16*  xb    = (bf16*)alloc((size_t)M_ROWS * E_DIM * 2);
    bf16*  BuH   = (bf16*)alloc((size_t)M_ROWS * 2048 * 2);
    bf16*  BscT  = (bf16*)alloc((size_t)2048 * 1024 * 2);
    bf16*  Win_b = (bf16*)alloc((size_t)512 * 1024 * 2);
    bf16*  Cr_b  = (bf16*)alloc((size_t)1024 * 1024 * 2);
    bf16*  Ci_b  = (bf16*)alloc((size_t)1024 * 1024 * 2);
    bf16*  WoT   = (bf16*)alloc((size_t)512 * 1024 * 2);
    bf16*  WoTD  = (bf16*)alloc((size_t)512 * 1024 * 2);
    bf16*  WBcat = (bf16*)alloc((size_t)2048 * 512 * 2);
    bf16*  Bfin  = (bf16*)alloc((size_t)512 * 2560 * 2);
    float* LamR  = (float*)alloc(1024 * 4);
    float* LamI  = (float*)alloc(1024 * 4);
    float* gvec  = (float*)alloc(1024 * 4);
    float* c_bu  = (float*)alloc(2048 * 4);
    float* biasO = (float*)alloc(512 * 4);
    float2* carry = (float2*)alloc((size_t)NCHUNK * 8192 * 8);
    float2* Sbuf  = (float2*)alloc((size_t)NCHUNK * 8192 * 8);

    // prep + merged converts/transposes
    k_prep<<<4, 256, 0, stream>>>(nu_log, theta_log, gamma_log, LamR, LamI, gvec);
    k_conv_all<<<10752, 256, 0, stream>>>(x, W_in, C_real, C_imag, xb, Win_b, Cr_b, Ci_b);
    k_transpose_all<<<3072, 256, 0, stream>>>(B_real, B_imag, W_out, gvec, Dvec, BscT, WoT, WoTD);

    // bias vectors (zero first; ws is re-poisoned 0xAA before every call)
    hipMemsetAsync(c_bu, 0, 2048 * 4, stream);
    hipMemsetAsync(biasO, 0, 512 * 4, stream);
    k_bias_bu<<<64, 256, 0, stream>>>(b_in, gvec, B_real, B_imag, c_bu);
    k_bias_out<<<16, 256, 0, stream>>>(b_out, b_in, Dvec, W_out, biasO);

    // precompute folds: one batched launch (144 blocks)
    k_gemm4<<<144, 256, 0, stream>>>(BscT, Win_b, WoT, WoTD, Cr_b, Ci_b, WBcat, Bfin);

    // G1: BuH[16384,2048] = xb @ WBcat^T + c_bu   (Bu real|imag)
    k_g1<<<2048, 256, 0, stream>>>(xb, WBcat, BuH, c_bu);

    // scan: h_t = Lam*h_{t-1} + Bu_t  (in place, bf16 out)
    k_scan_carry<<<NCHUNK * 8192 / 256, 256, 0, stream>>>(BuH, LamR, LamI, carry);
    k_scan_combine<<<32, 256, 0, stream>>>(carry, Sbuf, LamR, LamI);
    k_scan_apply<<<NCHUNK * 8192 / 256, 256, 0, stream>>>(BuH, LamR, LamI, Sbuf);

    // G2: out[16384,512] = [h_r|h_i|xb] @ Bfin^T + biasO
    k_g2<<<512, 256, 0, stream>>>(BuH, xb, Bfin, out, biasO);
}